// Round 15
// baseline (369.307 us; speedup 1.0000x reference)
//
#include <hip/hip_runtime.h>
#include <hip/hip_fp16.h>
#include <math.h>

#define TB 256

typedef _Float16 half8v __attribute__((ext_vector_type(8)));
typedef float float4v __attribute__((ext_vector_type(4)));

static __device__ __forceinline__ int edge_src(const int* ei, int E, int e) {
    return (e < E) ? ei[e] : (e - E);
}
static __device__ __forceinline__ int edge_dst(const int* ei, int E, int e) {
    return (e < E) ? ei[E + e] : (e - E);
}

// ---------------- CSR build ----------------
__global__ void csr_count(const int* __restrict__ ei, int E, int Etot, int* __restrict__ cnt) {
    int e = blockIdx.x * blockDim.x + threadIdx.x;
    if (e >= Etot) return;
    atomicAdd(&cnt[edge_dst(ei, E, e)], 1);
}

__global__ __launch_bounds__(256) void scan_phase1(const int* __restrict__ cnt,
                                                   int* __restrict__ incl,
                                                   int* __restrict__ bsum, int n) {
    __shared__ int sdata[256];
    int t = threadIdx.x;
    int base = blockIdx.x * 256;
    int v = (base + t < n) ? cnt[base + t] : 0;
    for (int d = 1; d < 256; d <<= 1) {
        sdata[t] = v; __syncthreads();
        if (t >= d) v += sdata[t - d];
        __syncthreads();
    }
    if (base + t < n) incl[base + t] = v;
    if (t == 255) bsum[blockIdx.x] = v;
}

__global__ void scan_phase2(int* bsum, int nb) {
    __shared__ int sdata[256];
    int t = threadIdx.x;
    int v = (t < nb) ? bsum[t] : 0;
    for (int d = 1; d < 256; d <<= 1) {
        sdata[t] = v; __syncthreads();
        if (t >= d) v += sdata[t - d];
        __syncthreads();
    }
    if (t < nb) bsum[t] = v;
}

__global__ __launch_bounds__(256) void scan_phase3(const int* __restrict__ incl,
                                                   const int* __restrict__ bsum,
                                                   int* __restrict__ off, int n) {
    int i = blockIdx.x * 256 + threadIdx.x;
    if (i < n) off[i + 1] = incl[i] + (blockIdx.x ? bsum[blockIdx.x - 1] : 0);
    if (i == 0) off[0] = 0;
}

__global__ void csr_fill(const int* __restrict__ ei, int E, int Etot,
                         const int* __restrict__ off, int* __restrict__ cur,
                         int* __restrict__ esrc) {
    int e = blockIdx.x * blockDim.x + threadIdx.x;
    if (e >= Etot) return;
    int d = edge_dst(ei, E, e);
    int pos = atomicAdd(&cur[d], 1);
    esrc[off[d] + pos] = edge_src(ei, E, e);
}

// ------ merged weight prep ------
__global__ void prep_weights(const float* __restrict__ W_e0, const float* __restrict__ g_w1,
                             const float* __restrict__ W_e1, const float* __restrict__ W_d1,
                             __half* __restrict__ wt_e0, __half* __restrict__ wt_g1,
                             __half* __restrict__ wst_e1, __half* __restrict__ wst_d1) {
    int i = blockIdx.x * blockDim.x + threadIdx.x;
    if (i < 65536) {
        int nn = i / 128, kk = i % 128;
        wt_e0[i] = __float2half(W_e0[kk * 512 + nn]);
    } else if (i < 69632) {
        int j = i - 65536;
        int nn = j / 64, kk = j % 64;
        wt_g1[j] = __float2half(g_w1[kk * 64 + nn]);
    } else if (i < 102400) {
        int j = i - 69632;
        int c = j / 512, rem = j % 512;
        int h = rem / 64, k = rem % 64;
        wst_e1[j] = __float2half(W_e1[(size_t)k * 512 + h * 64 + c]);
    } else if (i < 110592) {
        int j = i - 102400;
        int c = j / 64, k = j % 64;
        wst_d1[j] = __float2half(W_d1[(size_t)k * 128 + c]);
    }
}

__global__ void prep_ws(const float* __restrict__ W_e0, const float* __restrict__ a_s_e0,
                        const float* __restrict__ a_d_e0,
                        const float* __restrict__ W_e1, const float* __restrict__ a_s_e1,
                        const float* __restrict__ a_d_e1,
                        const float* __restrict__ W_d1, const float* __restrict__ a_s_d1,
                        const float* __restrict__ a_d_d1,
                        float* __restrict__ ws_e0, float* __restrict__ wd_e0,
                        float* __restrict__ ws_e1, float* __restrict__ wd_e1,
                        float* __restrict__ ws_d1, float* __restrict__ wd_d1) {
    int i = blockIdx.x * blockDim.x + threadIdx.x;
    const float* W; const float* as_; const float* ad_;
    float* ws; float* wd;
    int K, H, C, j;
    if (i < 1024) { j = i; K = 128; H = 8; C = 64; W = W_e0; as_ = a_s_e0; ad_ = a_d_e0; ws = ws_e0; wd = wd_e0; }
    else if (i < 1536) { j = i - 1024; K = 64; H = 8; C = 64; W = W_e1; as_ = a_s_e1; ad_ = a_d_e1; ws = ws_e1; wd = wd_e1; }
    else if (i < 1600) { j = i - 1536; K = 64; H = 1; C = 128; W = W_d1; as_ = a_s_d1; ad_ = a_d_d1; ws = ws_d1; wd = wd_d1; }
    else return;
    int h = j / K, k = j % K;
    const float* wrow = W + (size_t)k * H * C + h * C;
    float s = 0.f, d = 0.f;
    for (int c = 0; c < C; ++c) {
        s += wrow[c] * as_[h * C + c];
        d += wrow[c] * ad_[h * C + c];
    }
    ws[j] = s;
    wd[j] = d;
}

// ---------------- wide MFMA GEMM for enc0: BM=64, BN=128, K=128 -------------
__global__ __launch_bounds__(256) void gemm_mfma_wide(const __half* __restrict__ A,
                                                      const __half* __restrict__ BT,
                                                      __half* __restrict__ C,
                                                      int M, int N) {
    constexpr int K = 128, KP = 136;
    __shared__ __align__(16) __half As[64 * KP];
    __shared__ __align__(16) __half Bs[128 * KP];
    int tid = threadIdx.x;
    int bm = blockIdx.y * 64, bn = blockIdx.x * 128;
    for (int idx = tid; idx < 64 * 16; idx += 256) {
        int row = idx >> 4, ko = (idx & 15) * 8;
        uint4 v = make_uint4(0u, 0u, 0u, 0u);
        int gr = bm + row;
        if (gr < M) v = *(const uint4*)(A + (size_t)gr * K + ko);
        *(uint4*)(&As[row * KP + ko]) = v;
    }
    for (int idx = tid; idx < 128 * 16; idx += 256) {
        int row = idx >> 4, ko = (idx & 15) * 8;
        *(uint4*)(&Bs[row * KP + ko]) = *(const uint4*)(BT + (size_t)(bn + row) * K + ko);
    }
    __syncthreads();
    int wv_ = tid >> 6, l = tid & 63;
    int lr = l & 15, g = l >> 4;
    float4v acc[8] = {{0,0,0,0},{0,0,0,0},{0,0,0,0},{0,0,0,0},
                      {0,0,0,0},{0,0,0,0},{0,0,0,0},{0,0,0,0}};
    const __half* ap = &As[(16 * wv_ + lr) * KP + 8 * g];
    const __half* bp = &Bs[lr * KP + 8 * g];
#pragma unroll
    for (int k0 = 0; k0 < K; k0 += 32) {
        half8v af = *reinterpret_cast<const half8v*>(ap + k0);
#pragma unroll
        for (int nt = 0; nt < 8; ++nt) {
            half8v bf = *reinterpret_cast<const half8v*>(bp + nt * 16 * KP + k0);
            acc[nt] = __builtin_amdgcn_mfma_f32_16x16x32_f16(af, bf, acc[nt], 0, 0, 0);
        }
    }
#pragma unroll
    for (int nt = 0; nt < 8; ++nt) {
#pragma unroll
        for (int r = 0; r < 4; ++r) {
            int grow = bm + 16 * wv_ + 4 * g + r;
            if (grow < M)
                C[(size_t)grow * N + bn + nt * 16 + lr] = __float2half(acc[nt][r]);
        }
    }
}

// ------- fused cast + scores (enc0) --------
template <int K, int H>
__global__ __launch_bounds__(256) void scores_cast_nt(const float* __restrict__ X,
                                                      __half* __restrict__ X16,
                                                      const float* __restrict__ ws,
                                                      const float* __restrict__ wd,
                                                      float* __restrict__ es,
                                                      float* __restrict__ ed, int N) {
    int n = blockIdx.x * blockDim.x + threadIdx.x;
    if (n >= N) return;
    const float* row = X + (size_t)n * K;
    __half* row16 = X16 + (size_t)n * K;
    float s[H] = {}, d[H] = {};
#pragma unroll
    for (int k0 = 0; k0 < K; k0 += 8) {
        float4 a0 = *(const float4*)(row + k0);
        float4 a1 = *(const float4*)(row + k0 + 4);
        float a[8] = {a0.x, a0.y, a0.z, a0.w, a1.x, a1.y, a1.z, a1.w};
        __half2 h0 = __floats2half2_rn(a[0], a[1]);
        __half2 h1 = __floats2half2_rn(a[2], a[3]);
        __half2 h2 = __floats2half2_rn(a[4], a[5]);
        __half2 h3 = __floats2half2_rn(a[6], a[7]);
        uint4 pk;
        pk.x = *(unsigned*)&h0; pk.y = *(unsigned*)&h1;
        pk.z = *(unsigned*)&h2; pk.w = *(unsigned*)&h3;
        *(uint4*)(row16 + k0) = pk;
#pragma unroll
        for (int h = 0; h < H; ++h)
#pragma unroll
            for (int q = 0; q < 8; ++q) {
                s[h] += a[q] * ws[h * K + k0 + q];
                d[h] += a[q] * wd[h * K + k0 + q];
            }
    }
#pragma unroll
    for (int h = 0; h < H; ++h) {
        es[(size_t)n * H + h] = s[h];
        ed[(size_t)n * H + h] = d[h];
    }
}

// ------- enc0 gather (8-edge chunked) + FUSED enc1 scores -------------------
// Epilogue: lanes 0-7 hold bufA row (8ch each, post-relu) -> compute enc1
// es/ed dots in-register + 3-step butterfly over lanes 0-7.
__global__ __launch_bounds__(256) void gat_gather_h8s(const __half* __restrict__ hsrc,
                                                      const float* __restrict__ es,
                                                      const float* __restrict__ ed,
                                                      const int* __restrict__ off,
                                                      const int* __restrict__ esrc,
                                                      const float* __restrict__ bias,
                                                      const float* __restrict__ ws2,
                                                      const float* __restrict__ wd2,
                                                      __half* __restrict__ out,
                                                      float* __restrict__ es2,
                                                      float* __restrict__ ed2, int N) {
    constexpr int HC = 512;
    int n = (blockIdx.x * blockDim.x + threadIdx.x) >> 6;
    int lane = threadIdx.x & 63;
    if (n >= N) return;
    int hd = lane >> 3;
    int k8 = lane >> 3, h8 = lane & 7;
    int j0 = off[n], j1 = off[n + 1];

    float edl = ed[(size_t)n * 8 + h8];

    float acc[8] = {};
    float denacc = 0.f;
    for (int j = j0; j < j1; j += 8) {
        int jj = j + k8;
        int jc = (jj < j1) ? jj : (j1 - 1);
        int sidx = esrc[jc];
        float v = es[(size_t)sidx * 8 + h8] + edl;
        v = (v > 0.f) ? v : 0.2f * v;
        float pm = (jj < j1) ? expf(v) : 0.f;
        denacc += pm;
        uint4 rw[8];
#pragma unroll
        for (int k = 0; k < 8; ++k) {
            int sb = __shfl(sidx, k * 8);
            rw[k] = *(const uint4*)(hsrc + (size_t)sb * HC + 8 * lane);
        }
#pragma unroll
        for (int k = 0; k < 8; ++k) {
            float a = __shfl(pm, k * 8 + hd);
            const __half* hv = (const __half*)&rw[k];
#pragma unroll
            for (int q = 0; q < 8; ++q) acc[q] += a * __half2float(hv[q]);
        }
    }

    float den = denacc;
#pragma unroll
    for (int o = 8; o < 64; o <<= 1) den += __shfl_xor(den, o);
    float dv = __shfl(den, hd) + 1e-16f;

#pragma unroll
    for (int q = 0; q < 8; ++q) acc[q] /= dv;
#pragma unroll
    for (int o = 8; o < 64; o <<= 1)
#pragma unroll
        for (int q = 0; q < 8; ++q) acc[q] += __shfl_xor(acc[q], o);

    if (lane < 8) {
        int cbase = 8 * lane;
        float r[8];
#pragma unroll
        for (int q = 0; q < 8; ++q)
            r[q] = fmaxf(acc[q] * 0.125f + bias[cbase + q], 0.f);  // relu
        __half2 p0 = __floats2half2_rn(r[0], r[1]);
        __half2 p1 = __floats2half2_rn(r[2], r[3]);
        __half2 p2 = __floats2half2_rn(r[4], r[5]);
        __half2 p3 = __floats2half2_rn(r[6], r[7]);
        uint4 pk;
        pk.x = *(unsigned*)&p0; pk.y = *(unsigned*)&p1;
        pk.z = *(unsigned*)&p2; pk.w = *(unsigned*)&p3;
        *(uint4*)(out + (size_t)n * 64 + cbase) = pk;
        // fused enc1 scores
        float ps[8] = {}, pd[8] = {};
#pragma unroll
        for (int h = 0; h < 8; ++h)
#pragma unroll
            for (int q = 0; q < 8; ++q) {
                ps[h] += r[q] * ws2[h * 64 + cbase + q];
                pd[h] += r[q] * wd2[h * 64 + cbase + q];
            }
#pragma unroll
        for (int o = 1; o < 8; o <<= 1)
#pragma unroll
            for (int h = 0; h < 8; ++h) {
                ps[h] += __shfl_xor(ps[h], o);
                pd[h] += __shfl_xor(pd[h], o);
            }
        es2[(size_t)n * 8 + lane] = ps[lane];
        ed2[(size_t)n * 8 + lane] = pd[lane];
    }
}

// ------- enc1 z-gather: lane=(head h, slice q); zero shuffles ---------------
__global__ __launch_bounds__(256) void gat_gather_zh8(const __half* __restrict__ A,
                                                      const float* __restrict__ es,
                                                      const float* __restrict__ ed,
                                                      const int* __restrict__ off,
                                                      const int* __restrict__ esrc,
                                                      __half* __restrict__ z, int N) {
    int n = (blockIdx.x * blockDim.x + threadIdx.x) >> 6;
    int lane = threadIdx.x & 63;
    if (n >= N) return;
    int h = lane >> 3, q = lane & 7;
    int j0 = off[n], j1 = off[n + 1];
    float edv = ed[(size_t)n * 8 + h];

    float acc[8] = {};
    float den = 0.f;
    int j = j0;
    for (; j + 1 < j1; j += 2) {
        int s0 = esrc[j], s1 = esrc[j + 1];
        float v0 = es[(size_t)s0 * 8 + h] + edv;
        float v1 = es[(size_t)s1 * 8 + h] + edv;
        v0 = (v0 > 0.f) ? v0 : 0.2f * v0;
        v1 = (v1 > 0.f) ? v1 : 0.2f * v1;
        float p0 = expf(v0), p1 = expf(v1);
        den += p0 + p1;
        uint4 r0 = *(const uint4*)(A + (size_t)s0 * 64 + 8 * q);
        uint4 r1 = *(const uint4*)(A + (size_t)s1 * 64 + 8 * q);
        const __half* h0 = (const __half*)&r0;
        const __half* h1 = (const __half*)&r1;
#pragma unroll
        for (int k = 0; k < 8; ++k)
            acc[k] += p0 * __half2float(h0[k]) + p1 * __half2float(h1[k]);
    }
    if (j < j1) {
        int s0 = esrc[j];
        float v0 = es[(size_t)s0 * 8 + h] + edv;
        v0 = (v0 > 0.f) ? v0 : 0.2f * v0;
        float p0 = expf(v0);
        den += p0;
        uint4 r0 = *(const uint4*)(A + (size_t)s0 * 64 + 8 * q);
        const __half* h0 = (const __half*)&r0;
#pragma unroll
        for (int k = 0; k < 8; ++k) acc[k] += p0 * __half2float(h0[k]);
    }

    float inv = 1.f / ((den + 1e-16f) * 8.f);
    float r[8];
#pragma unroll
    for (int k = 0; k < 8; ++k) r[k] = acc[k] * inv;
    __half2 p0 = __floats2half2_rn(r[0], r[1]);
    __half2 p1 = __floats2half2_rn(r[2], r[3]);
    __half2 p2 = __floats2half2_rn(r[4], r[5]);
    __half2 p3 = __floats2half2_rn(r[6], r[7]);
    uint4 pk;
    pk.x = *(unsigned*)&p0; pk.y = *(unsigned*)&p1;
    pk.z = *(unsigned*)&p2; pk.w = *(unsigned*)&p3;
    *(uint4*)(z + (size_t)n * 512 + h * 64 + 8 * q) = pk;
}

// -------- dec1 z-gather, 8-edge chunked ----------------
__global__ __launch_bounds__(256) void gat_gather_z8(const __half* __restrict__ A,
                                                     const float* __restrict__ es,
                                                     const float* __restrict__ ed,
                                                     const int* __restrict__ off,
                                                     const int* __restrict__ esrc,
                                                     __half* __restrict__ z, int N) {
    int n = (blockIdx.x * blockDim.x + threadIdx.x) >> 6;
    int lane = threadIdx.x & 63;
    if (n >= N) return;
    int k8 = lane >> 3, q8 = lane & 7;
    int j0 = off[n], j1 = off[n + 1];
    float edv = ed[n];

    float acc[8] = {};
    float denacc = 0.f;
    for (int j = j0; j < j1; j += 8) {
        int jj = j + k8;
        int jc = (jj < j1) ? jj : (j1 - 1);
        int sidx = esrc[jc];
        float v = es[sidx] + edv;
        v = (v > 0.f) ? v : 0.2f * v;
        float pm = (jj < j1) ? expf(v) : 0.f;
        denacc += pm;
        uint4 rw = *(const uint4*)(A + (size_t)sidx * 64 + 8 * q8);
        const __half* hv = (const __half*)&rw;
#pragma unroll
        for (int q = 0; q < 8; ++q) acc[q] += pm * __half2float(hv[q]);
    }

    float den = denacc;
#pragma unroll
    for (int o = 8; o < 64; o <<= 1) {
        den += __shfl_xor(den, o);
#pragma unroll
        for (int q = 0; q < 8; ++q) acc[q] += __shfl_xor(acc[q], o);
    }
    float inv = 1.f / (den + 1e-16f);
    if (lane < 8) {
        float r[8];
#pragma unroll
        for (int q = 0; q < 8; ++q) r[q] = acc[q] * inv;
        __half2 p0 = __floats2half2_rn(r[0], r[1]);
        __half2 p1 = __floats2half2_rn(r[2], r[3]);
        __half2 p2 = __floats2half2_rn(r[4], r[5]);
        __half2 p3 = __floats2half2_rn(r[6], r[7]);
        uint4 pk;
        pk.x = *(unsigned*)&p0; pk.y = *(unsigned*)&p1;
        pk.z = *(unsigned*)&p2; pk.w = *(unsigned*)&p3;
        *(uint4*)(z + (size_t)n * 64 + 8 * lane) = pk;
    }
}

// ---------------- K-tiled MFMA GEMM with bias/relu (z-path) ------------------
template <int KK, typename OUTT, bool RELU>
__global__ __launch_bounds__(256) void gemm_kt(const __half* __restrict__ A,
                                               const __half* __restrict__ BT,
                                               const float* __restrict__ bias,
                                               OUTT* __restrict__ C,
                                               int M, int Nout) {
    __shared__ __align__(16) __half As[64 * 72];
    __shared__ __align__(16) __half Bs[64 * 72];
    int tid = threadIdx.x;
    int bm = blockIdx.y * 64, bn = blockIdx.x * 64;
    int wv = tid >> 6, l = tid & 63, lr = l & 15, g = l >> 4;
    float4v acc[4] = {{0.f, 0.f, 0.f, 0.f}, {0.f, 0.f, 0.f, 0.f},
                      {0.f, 0.f, 0.f, 0.f}, {0.f, 0.f, 0.f, 0.f}};
    for (int kc = 0; kc < KK; kc += 64) {
        __syncthreads();
        for (int idx = tid; idx < 512; idx += 256) {
            int row = idx >> 3, ko = (idx & 7) * 8;
            uint4 v = make_uint4(0u, 0u, 0u, 0u);
            int gr = bm + row;
            if (gr < M) v = *(const uint4*)(A + (size_t)gr * KK + kc + ko);
            *(uint4*)(&As[row * 72 + ko]) = v;
            uint4 wvv = *(const uint4*)(BT + (size_t)(bn + row) * KK + kc + ko);
            *(uint4*)(&Bs[row * 72 + ko]) = wvv;
        }
        __syncthreads();
#pragma unroll
        for (int k0 = 0; k0 < 64; k0 += 32) {
            half8v af = *reinterpret_cast<const half8v*>(&As[(16 * wv + lr) * 72 + k0 + 8 * g]);
#pragma unroll
            for (int nt = 0; nt < 4; ++nt) {
                half8v bf = *reinterpret_cast<const half8v*>(&Bs[(nt * 16 + lr) * 72 + k0 + 8 * g]);
                acc[nt] = __builtin_amdgcn_mfma_f32_16x16x32_f16(af, bf, acc[nt], 0, 0, 0);
            }
        }
    }
#pragma unroll
    for (int nt = 0; nt < 4; ++nt) {
        float b = bias[bn + nt * 16 + lr];
#pragma unroll
        for (int r = 0; r < 4; ++r) {
            int grow = bm + 16 * wv + 4 * g + r;
            if (grow < M) {
                float c = acc[nt][r] + b;
                if (RELU) c = fmaxf(c, 0.f);
                if constexpr (sizeof(OUTT) == 2)
                    C[(size_t)grow * Nout + bn + nt * 16 + lr] = __float2half(c);
                else
                    C[(size_t)grow * Nout + bn + nt * 16 + lr] = c;
            }
        }
    }
}

// ------- dec0 gather (8-edge chunked) + FUSED dec1 scores -------------------
__global__ __launch_bounds__(256) void gat_gather_d08s(const float* __restrict__ hsrc,
                                                       const float* __restrict__ es16,
                                                       const float* __restrict__ ed16,
                                                       const int* __restrict__ off,
                                                       const int* __restrict__ esrc,
                                                       const int* __restrict__ batch,
                                                       const float* __restrict__ bias,
                                                       const float* __restrict__ ws2,
                                                       const float* __restrict__ wd2,
                                                       __half* __restrict__ out,
                                                       float* __restrict__ es2,
                                                       float* __restrict__ ed2, int N) {
    int n = (blockIdx.x * blockDim.x + threadIdx.x) >> 6;
    int lane = threadIdx.x & 63;
    if (n >= N) return;
    int k8 = lane >> 3, q8 = lane & 7;
    int j0 = off[n], j1 = off[n + 1];
    float edv = ed16[batch[n]];

    float acc[8] = {};
    float denacc = 0.f;
    for (int j = j0; j < j1; j += 8) {
        int jj = j + k8;
        int jc = (jj < j1) ? jj : (j1 - 1);
        int g = batch[esrc[jc]];
        float v = es16[g] + edv;
        v = (v > 0.f) ? v : 0.2f * v;
        float pm = (jj < j1) ? expf(v) : 0.f;
        denacc += pm;
        const float* row = hsrc + (size_t)g * 64 + 8 * q8;
        float4 r0 = *(const float4*)row;
        float4 r1 = *(const float4*)(row + 4);
        acc[0] += pm * r0.x; acc[1] += pm * r0.y;
        acc[2] += pm * r0.z; acc[3] += pm * r0.w;
        acc[4] += pm * r1.x; acc[5] += pm * r1.y;
        acc[6] += pm * r1.z; acc[7] += pm * r1.w;
    }

    float den = denacc;
#pragma unroll
    for (int o = 8; o < 64; o <<= 1) {
        den += __shfl_xor(den, o);
#pragma unroll
        for (int q = 0; q < 8; ++q) acc[q] += __shfl_xor(acc[q], o);
    }
    float inv = 1.f / (den + 1e-16f);
    if (lane < 8) {
        int cbase = 8 * lane;
        float r[8];
#pragma unroll
        for (int q = 0; q < 8; ++q) r[q] = fmaxf(acc[q] * inv + bias[cbase + q], 0.f);
        __half2 p0 = __floats2half2_rn(r[0], r[1]);
        __half2 p1 = __floats2half2_rn(r[2], r[3]);
        __half2 p2 = __floats2half2_rn(r[4], r[5]);
        __half2 p3 = __floats2half2_rn(r[6], r[7]);
        uint4 pk;
        pk.x = *(unsigned*)&p0; pk.y = *(unsigned*)&p1;
        pk.z = *(unsigned*)&p2; pk.w = *(unsigned*)&p3;
        *(uint4*)(out + (size_t)n * 64 + cbase) = pk;
        // fused dec1 scores (H=1)
        float ps = 0.f, pd = 0.f;
#pragma unroll
        for (int q = 0; q < 8; ++q) {
            ps += r[q] * ws2[cbase + q];
            pd += r[q] * wd2[cbase + q];
        }
#pragma unroll
        for (int o = 1; o < 8; o <<= 1) {
            ps += __shfl_xor(ps, o);
            pd += __shfl_xor(pd, o);
        }
        if (lane == 0) {
            es2[n] = ps;
            ed2[n] = pd;
        }
    }
}

// ---- gate via MFMA + FUSED pooled sum (bufB tile already in LDS) ------------
__global__ __launch_bounds__(256) void gate_pool_mfma(const __half* __restrict__ A,
                                                      const __half* __restrict__ BT,
                                                      const float* __restrict__ b1,
                                                      const float* __restrict__ w2,
                                                      const float* __restrict__ b2,
                                                      const int* __restrict__ batch,
                                                      float* __restrict__ pg,
                                                      float* __restrict__ gden,
                                                      float* __restrict__ pooled, int M) {
    constexpr int KP = 72;
    __shared__ __align__(16) __half As[64 * KP];
    __shared__ __align__(16) __half Bs[64 * KP];
    __shared__ float part[16];
    __shared__ float sp[64];
    __shared__ int sb[64];
    int tid = threadIdx.x;
    if (tid < 16) part[tid] = 0.f;
    int bm = blockIdx.x * 64;
    for (int idx = tid; idx < 512; idx += 256) {
        int row = idx >> 3, ko = (idx & 7) * 8;
        uint4 v = make_uint4(0u, 0u, 0u, 0u);
        int gr = bm + row;
        if (gr < M) v = *(const uint4*)(A + (size_t)gr * 64 + ko);
        *(uint4*)(&As[row * KP + ko]) = v;
        uint4 wvv = *(const uint4*)(BT + (size_t)row * 64 + ko);
        *(uint4*)(&Bs[row * KP + ko]) = wvv;
    }
    __syncthreads();
    int wv_ = tid >> 6, l = tid & 63;
    int lr = l & 15, g = l >> 4;
    float4v acc[4] = {{0.f, 0.f, 0.f, 0.f}, {0.f, 0.f, 0.f, 0.f},
                      {0.f, 0.f, 0.f, 0.f}, {0.f, 0.f, 0.f, 0.f}};
    const __half* ap = &As[(16 * wv_ + lr) * KP + 8 * g];
    const __half* bp = &Bs[lr * KP + 8 * g];
#pragma unroll
    for (int k0 = 0; k0 < 64; k0 += 32) {
        half8v af = *reinterpret_cast<const half8v*>(ap + k0);
#pragma unroll
        for (int nt = 0; nt < 4; ++nt) {
            half8v bf = *reinterpret_cast<const half8v*>(bp + nt * 16 * KP + k0);
            acc[nt] = __builtin_amdgcn_mfma_f32_16x16x32_f16(af, bf, acc[nt], 0, 0, 0);
        }
    }
    float partial[4];
#pragma unroll
    for (int r = 0; r < 4; ++r) {
        float t = 0.f;
#pragma unroll
        for (int nt = 0; nt < 4; ++nt) {
            int col = nt * 16 + lr;
            float tv = acc[nt][r] + b1[col];
            tv = fmaxf(tv, 0.f);
            t += tv * w2[col];
        }
        partial[r] = t;
    }
#pragma unroll
    for (int o = 1; o < 16; o <<= 1)
#pragma unroll
        for (int r = 0; r < 4; ++r) partial[r] += __shfl_xor(partial[r], o);
    if (lr == 0) {
        float bb = b2[0];
#pragma unroll
        for (int r = 0; r < 4; ++r) {
            int row = 16 * wv_ + 4 * g + r;
            int grow = bm + row;
            if (grow < M) {
                float p = expf(partial[r] + bb);
                pg[grow] = p;
                int bg = batch[grow];
                sp[row] = p;
                sb[row] = bg;
                atomicAdd(&part[bg], p);
            }
        }
    }
    __syncthreads();
    if (tid < 16 && part[tid] != 0.f) atomicAdd(&gden[tid], part[tid]);
    // fused pooled sum: ch = tid (threads 0..63), rows split at graph bounds
    if (tid < 64) {
        int nrows = min(64, M - bm);
        int curg = sb[0];
        float acc2 = 0.f;
        for (int row = 0; row < nrows; ++row) {
            int g2 = sb[row];
            if (g2 != curg) {
                atomicAdd(&pooled[curg * 64 + tid], acc2);
                acc2 = 0.f;
                curg = g2;
            }
            acc2 += sp[row] * __half2float(As[row * KP + tid]);
        }
        atomicAdd(&pooled[curg * 64 + tid], acc2);
    }
}

__global__ void dec_prep(const float* __restrict__ pooled, const float* __restrict__ gden,
                         const float* __restrict__ Wd0, const float* __restrict__ asd,
                         const float* __restrict__ add, float* __restrict__ hd016,
                         float* __restrict__ es16, float* __restrict__ ed16) {
    int g = blockIdx.x;
    int lane = threadIdx.x;
    float pn = pooled[g * 64 + lane] / (gden[g] + 1e-16f);
    float o = 0.f;
    for (int c = 0; c < 64; ++c) o += __shfl(pn, c) * Wd0[c * 64 + lane];
    hd016[g * 64 + lane] = o;
    float s = o * asd[lane], d = o * add[lane];
#pragma unroll
    for (int off = 32; off; off >>= 1) {
        s += __shfl_xor(s, off);
        d += __shfl_xor(d, off);
    }
    if (lane == 0) {
        es16[g] = s;
        ed16[g] = d;
    }
}

// ---------------- host ----------------
static inline int cdiv(int a, int b) { return (a + b - 1) / b; }

extern "C" void kernel_launch(void* const* d_in, const int* in_sizes, int n_in,
                              void* d_out, int out_size, void* d_ws, size_t ws_size,
                              hipStream_t stream) {
    const float* x      = (const float*)d_in[0];
    const int*   ei     = (const int*)  d_in[1];
    const int*   batch  = (const int*)  d_in[2];
    const float* W_e0   = (const float*)d_in[3];
    const float* a_s_e0 = (const float*)d_in[4];
    const float* a_d_e0 = (const float*)d_in[5];
    const float* b_e0   = (const float*)d_in[6];
    const float* W_e1   = (const float*)d_in[7];
    const float* a_s_e1 = (const float*)d_in[8];
    const float* a_d_e1 = (const float*)d_in[9];
    const float* b_e1   = (const float*)d_in[10];
    const float* W_d0   = (const float*)d_in[11];
    const float* a_s_d0 = (const float*)d_in[12];
    const float* a_d_d0 = (const float*)d_in[13];
    const float* b_d0   = (const float*)d_in[14];
    const float* W_d1   = (const float*)d_in[15];
    const float* a_s_d1 = (const float*)d_in[16];
    const float* a_d_d1 = (const float*)d_in[17];
    const float* b_d1   = (const float*)d_in[18];
    const float* g_w1   = (const float*)d_in[19];
    const float* g_b1   = (const float*)d_in[20];
    const float* g_w2   = (const float*)d_in[21];
    const float* g_b2   = (const float*)d_in[22];

    const int N    = in_sizes[2];
    const int E    = in_sizes[1] / 2;
    const int Etot = E + N;
    const int Din  = in_sizes[0] / N;  // 128

    char* w = (char*)d_ws;
    size_t o = 0;
    auto alloc = [&](size_t bytes) -> void* {
        void* p = w + o;
        o = (o + bytes + 255) & ~(size_t)255;
        return p;
    };
    __half*   h16    = (__half*)  alloc((size_t)N * 512 * 2);  // enc0 h / enc1 z / dec1 z
    __half*   x16    = (__half*)  alloc((size_t)N * Din * 2);
    __half*   bufA   = (__half*)  alloc((size_t)N * 64 * 2);
    __half*   bufB   = (__half*)  alloc((size_t)N * 64 * 2);
    __half*   wt_e0  = (__half*)  alloc((size_t)512 * 128 * 2);
    __half*   wst_e1 = (__half*)  alloc((size_t)64 * 512 * 2);
    __half*   wst_d1 = (__half*)  alloc((size_t)128 * 64 * 2);
    __half*   wt_g1  = (__half*)  alloc((size_t)64 * 64 * 2);
    float*    ws_e0  = (float*)   alloc(8 * 128 * 4);
    float*    wd_e0  = (float*)   alloc(8 * 128 * 4);
    float*    ws_e1  = (float*)   alloc(8 * 64 * 4);
    float*    wd_e1  = (float*)   alloc(8 * 64 * 4);
    float*    ws_d1  = (float*)   alloc(64 * 4);
    float*    wd_d1  = (float*)   alloc(64 * 4);
    float*    es     = (float*)   alloc((size_t)N * 8 * 4);
    float*    ed     = (float*)   alloc((size_t)N * 8 * 4);
    float*    pg     = (float*)   alloc((size_t)N * 4);
    int*      off    = (int*)     alloc((size_t)(N + 1) * 4);
    int*      cnt    = (int*)     alloc((size_t)N * 4);
    int*      esrc   = (int*)     alloc((size_t)Etot * 4);
    int*      bsum   = (int*)     alloc(256 * 4);
    float*    gden   = (float*)   alloc(16 * 4);      // gden+pooled: adjacent,
    float*    pooled = (float*)   alloc(16 * 64 * 4); // one memset covers both
    float*    hd016  = (float*)   alloc(16 * 64 * 4);
    float*    es16   = (float*)   alloc(16 * 4);
    float*    ed16   = (float*)   alloc(16 * 4);
    (void)ws_size; (void)n_in; (void)out_size;

    const int nodeWaveGrid = cdiv(N, 4);
    const int nodeThreadGrid = cdiv(N, TB);
    const int edgeGrid     = cdiv(Etot, TB);
    const int scanBlocks   = cdiv(N, 256);

    // ---- CSR ----
    hipMemsetAsync(cnt, 0, (size_t)N * 4, stream);
    csr_count<<<edgeGrid, TB, 0, stream>>>(ei, E, Etot, cnt);
    scan_phase1<<<scanBlocks, 256, 0, stream>>>(cnt, esrc /*temp incl*/, bsum, N);
    scan_phase2<<<1, 256, 0, stream>>>(bsum, scanBlocks);
    scan_phase3<<<scanBlocks, 256, 0, stream>>>(esrc, bsum, off, N);
    hipMemsetAsync(cnt, 0, (size_t)N * 4, stream);
    csr_fill<<<edgeGrid, TB, 0, stream>>>(ei, E, Etot, off, cnt, esrc);

    // ---- merged prep ----
    prep_weights<<<cdiv(110592, TB), TB, 0, stream>>>(W_e0, g_w1, W_e1, W_d1,
                                                      wt_e0, wt_g1, wst_e1, wst_d1);
    prep_ws<<<cdiv(1600, TB), TB, 0, stream>>>(W_e0, a_s_e0, a_d_e0,
                                               W_e1, a_s_e1, a_d_e1,
                                               W_d1, a_s_d1, a_d_d1,
                                               ws_e0, wd_e0, ws_e1, wd_e1, ws_d1, wd_d1);

    // ---- encoder layer 0 (H=8, relu) + fused enc1 scores ----
    scores_cast_nt<128, 8><<<nodeThreadGrid, TB, 0, stream>>>(x, x16, ws_e0, wd_e0, es, ed, N);
    {
        dim3 grid(512 / 128, cdiv(N, 64));
        gemm_mfma_wide<<<grid, TB, 0, stream>>>(x16, wt_e0, h16, N, 512);
    }
    gat_gather_h8s<<<nodeWaveGrid, TB, 0, stream>>>(
        h16, es, ed, off, esrc, b_e0, ws_e1, wd_e1, bufA, es, ed, N);

    // ---- encoder layer 1 (H=8, no relu): z-path ----
    gat_gather_zh8<<<nodeWaveGrid, TB, 0, stream>>>(bufA, es, ed, off, esrc, h16 /*z*/, N);
    {
        dim3 grid(1, cdiv(N, 64));
        gemm_kt<512, __half, false><<<grid, TB, 0, stream>>>(h16 /*z*/, wst_e1, b_e1, bufB, N, 64);
    }

    // ---- pooling (gate + pooled sum fused) ----
    hipMemsetAsync(gden, 0, 256 + 16 * 64 * 4, stream);  // covers gden pad + pooled
    gate_pool_mfma<<<cdiv(N, 64), TB, 0, stream>>>(bufB, wt_g1, g_b1, g_w2, g_b2,
                                                   batch, pg, gden, pooled, N);
    dec_prep<<<16, 64, 0, stream>>>(pooled, gden, W_d0, a_s_d0, a_d_d0, hd016, es16, ed16);

    // ---- decoder layer 0 (H=1, relu) + fused dec1 scores ----
    gat_gather_d08s<<<nodeWaveGrid, TB, 0, stream>>>(
        hd016, es16, ed16, off, esrc, batch, b_d0, ws_d1, wd_d1, bufA, es, ed, N);

    // ---- decoder layer 1 (H=1, C=128, no relu): z-path -> d_out ----
    gat_gather_z8<<<nodeWaveGrid, TB, 0, stream>>>(bufA, es, ed, off, esrc, h16 /*z*/, N);
    {
        dim3 grid(2, cdiv(N, 64));
        gemm_kt<64, float, false><<<grid, TB, 0, stream>>>(h16 /*z*/, wst_d1, b_d1, (float*)d_out, N, 128);
    }
}

// Round 16
// 327.459 us; speedup vs baseline: 1.1278x; 1.1278x over previous
//
#include <hip/hip_runtime.h>
#include <hip/hip_fp16.h>
#include <math.h>

#define TB 256

typedef _Float16 half8v __attribute__((ext_vector_type(8)));
typedef float float4v __attribute__((ext_vector_type(4)));

static __device__ __forceinline__ int edge_src(const int* ei, int E, int e) {
    return (e < E) ? ei[e] : (e - E);
}
static __device__ __forceinline__ int edge_dst(const int* ei, int E, int e) {
    return (e < E) ? ei[E + e] : (e - E);
}

// ---------------- CSR build ----------------
__global__ void csr_count(const int* __restrict__ ei, int E, int Etot, int* __restrict__ cnt) {
    int e = blockIdx.x * blockDim.x + threadIdx.x;
    if (e >= Etot) return;
    atomicAdd(&cnt[edge_dst(ei, E, e)], 1);
}

__global__ __launch_bounds__(256) void scan_phase1(const int* __restrict__ cnt,
                                                   int* __restrict__ incl,
                                                   int* __restrict__ bsum, int n) {
    __shared__ int sdata[256];
    int t = threadIdx.x;
    int base = blockIdx.x * 256;
    int v = (base + t < n) ? cnt[base + t] : 0;
    for (int d = 1; d < 256; d <<= 1) {
        sdata[t] = v; __syncthreads();
        if (t >= d) v += sdata[t - d];
        __syncthreads();
    }
    if (base + t < n) incl[base + t] = v;
    if (t == 255) bsum[blockIdx.x] = v;
}

__global__ void scan_phase2(int* bsum, int nb) {
    __shared__ int sdata[256];
    int t = threadIdx.x;
    int v = (t < nb) ? bsum[t] : 0;
    for (int d = 1; d < 256; d <<= 1) {
        sdata[t] = v; __syncthreads();
        if (t >= d) v += sdata[t - d];
        __syncthreads();
    }
    if (t < nb) bsum[t] = v;
}

__global__ __launch_bounds__(256) void scan_phase3(const int* __restrict__ incl,
                                                   const int* __restrict__ bsum,
                                                   int* __restrict__ off, int n) {
    int i = blockIdx.x * 256 + threadIdx.x;
    if (i < n) off[i + 1] = incl[i] + (blockIdx.x ? bsum[blockIdx.x - 1] : 0);
    if (i == 0) off[0] = 0;
}

__global__ void csr_fill(const int* __restrict__ ei, int E, int Etot,
                         const int* __restrict__ off, int* __restrict__ cur,
                         int* __restrict__ esrc) {
    int e = blockIdx.x * blockDim.x + threadIdx.x;
    if (e >= Etot) return;
    int d = edge_dst(ei, E, e);
    int pos = atomicAdd(&cur[d], 1);
    esrc[off[d] + pos] = edge_src(ei, E, e);
}

// ------ merged weight prep ------
__global__ void prep_weights(const float* __restrict__ W_e0, const float* __restrict__ g_w1,
                             const float* __restrict__ W_e1, const float* __restrict__ W_d1,
                             __half* __restrict__ wt_e0, __half* __restrict__ wt_g1,
                             __half* __restrict__ wst_e1, __half* __restrict__ wst_d1) {
    int i = blockIdx.x * blockDim.x + threadIdx.x;
    if (i < 65536) {
        int nn = i / 128, kk = i % 128;
        wt_e0[i] = __float2half(W_e0[kk * 512 + nn]);
    } else if (i < 69632) {
        int j = i - 65536;
        int nn = j / 64, kk = j % 64;
        wt_g1[j] = __float2half(g_w1[kk * 64 + nn]);
    } else if (i < 102400) {
        int j = i - 69632;
        int c = j / 512, rem = j % 512;
        int h = rem / 64, k = rem % 64;
        wst_e1[j] = __float2half(W_e1[(size_t)k * 512 + h * 64 + c]);
    } else if (i < 110592) {
        int j = i - 102400;
        int c = j / 64, k = j % 64;
        wst_d1[j] = __float2half(W_d1[(size_t)k * 128 + c]);
    }
}

__global__ void prep_ws(const float* __restrict__ W_e0, const float* __restrict__ a_s_e0,
                        const float* __restrict__ a_d_e0,
                        const float* __restrict__ W_e1, const float* __restrict__ a_s_e1,
                        const float* __restrict__ a_d_e1,
                        const float* __restrict__ W_d1, const float* __restrict__ a_s_d1,
                        const float* __restrict__ a_d_d1,
                        float* __restrict__ ws_e0, float* __restrict__ wd_e0,
                        float* __restrict__ ws_e1, float* __restrict__ wd_e1,
                        float* __restrict__ ws_d1, float* __restrict__ wd_d1) {
    int i = blockIdx.x * blockDim.x + threadIdx.x;
    const float* W; const float* as_; const float* ad_;
    float* ws; float* wd;
    int K, H, C, j;
    if (i < 1024) { j = i; K = 128; H = 8; C = 64; W = W_e0; as_ = a_s_e0; ad_ = a_d_e0; ws = ws_e0; wd = wd_e0; }
    else if (i < 1536) { j = i - 1024; K = 64; H = 8; C = 64; W = W_e1; as_ = a_s_e1; ad_ = a_d_e1; ws = ws_e1; wd = wd_e1; }
    else if (i < 1600) { j = i - 1536; K = 64; H = 1; C = 128; W = W_d1; as_ = a_s_d1; ad_ = a_d_d1; ws = ws_d1; wd = wd_d1; }
    else return;
    int h = j / K, k = j % K;
    const float* wrow = W + (size_t)k * H * C + h * C;
    float s = 0.f, d = 0.f;
    for (int c = 0; c < C; ++c) {
        s += wrow[c] * as_[h * C + c];
        d += wrow[c] * ad_[h * C + c];
    }
    ws[j] = s;
    wd[j] = d;
}

// ---------------- wide MFMA GEMM for enc0: BM=64, BN=128, K=128 -------------
__global__ __launch_bounds__(256) void gemm_mfma_wide(const __half* __restrict__ A,
                                                      const __half* __restrict__ BT,
                                                      __half* __restrict__ C,
                                                      int M, int N) {
    constexpr int K = 128, KP = 136;
    __shared__ __align__(16) __half As[64 * KP];
    __shared__ __align__(16) __half Bs[128 * KP];
    int tid = threadIdx.x;
    int bm = blockIdx.y * 64, bn = blockIdx.x * 128;
    for (int idx = tid; idx < 64 * 16; idx += 256) {
        int row = idx >> 4, ko = (idx & 15) * 8;
        uint4 v = make_uint4(0u, 0u, 0u, 0u);
        int gr = bm + row;
        if (gr < M) v = *(const uint4*)(A + (size_t)gr * K + ko);
        *(uint4*)(&As[row * KP + ko]) = v;
    }
    for (int idx = tid; idx < 128 * 16; idx += 256) {
        int row = idx >> 4, ko = (idx & 15) * 8;
        *(uint4*)(&Bs[row * KP + ko]) = *(const uint4*)(BT + (size_t)(bn + row) * K + ko);
    }
    __syncthreads();
    int wv_ = tid >> 6, l = tid & 63;
    int lr = l & 15, g = l >> 4;
    float4v acc[8] = {{0,0,0,0},{0,0,0,0},{0,0,0,0},{0,0,0,0},
                      {0,0,0,0},{0,0,0,0},{0,0,0,0},{0,0,0,0}};
    const __half* ap = &As[(16 * wv_ + lr) * KP + 8 * g];
    const __half* bp = &Bs[lr * KP + 8 * g];
#pragma unroll
    for (int k0 = 0; k0 < K; k0 += 32) {
        half8v af = *reinterpret_cast<const half8v*>(ap + k0);
#pragma unroll
        for (int nt = 0; nt < 8; ++nt) {
            half8v bf = *reinterpret_cast<const half8v*>(bp + nt * 16 * KP + k0);
            acc[nt] = __builtin_amdgcn_mfma_f32_16x16x32_f16(af, bf, acc[nt], 0, 0, 0);
        }
    }
#pragma unroll
    for (int nt = 0; nt < 8; ++nt) {
#pragma unroll
        for (int r = 0; r < 4; ++r) {
            int grow = bm + 16 * wv_ + 4 * g + r;
            if (grow < M)
                C[(size_t)grow * N + bn + nt * 16 + lr] = __float2half(acc[nt][r]);
        }
    }
}

// ------- fused cast + scores (enc0) --------
template <int K, int H>
__global__ __launch_bounds__(256) void scores_cast_nt(const float* __restrict__ X,
                                                      __half* __restrict__ X16,
                                                      const float* __restrict__ ws,
                                                      const float* __restrict__ wd,
                                                      float* __restrict__ es,
                                                      float* __restrict__ ed, int N) {
    int n = blockIdx.x * blockDim.x + threadIdx.x;
    if (n >= N) return;
    const float* row = X + (size_t)n * K;
    __half* row16 = X16 + (size_t)n * K;
    float s[H] = {}, d[H] = {};
#pragma unroll
    for (int k0 = 0; k0 < K; k0 += 8) {
        float4 a0 = *(const float4*)(row + k0);
        float4 a1 = *(const float4*)(row + k0 + 4);
        float a[8] = {a0.x, a0.y, a0.z, a0.w, a1.x, a1.y, a1.z, a1.w};
        __half2 h0 = __floats2half2_rn(a[0], a[1]);
        __half2 h1 = __floats2half2_rn(a[2], a[3]);
        __half2 h2 = __floats2half2_rn(a[4], a[5]);
        __half2 h3 = __floats2half2_rn(a[6], a[7]);
        uint4 pk;
        pk.x = *(unsigned*)&h0; pk.y = *(unsigned*)&h1;
        pk.z = *(unsigned*)&h2; pk.w = *(unsigned*)&h3;
        *(uint4*)(row16 + k0) = pk;
#pragma unroll
        for (int h = 0; h < H; ++h)
#pragma unroll
            for (int q = 0; q < 8; ++q) {
                s[h] += a[q] * ws[h * K + k0 + q];
                d[h] += a[q] * wd[h * K + k0 + q];
            }
    }
#pragma unroll
    for (int h = 0; h < H; ++h) {
        es[(size_t)n * H + h] = s[h];
        ed[(size_t)n * H + h] = d[h];
    }
}

// ------- scores, thread-per-node (fp16 input) ------
template <int K, int H>
__global__ __launch_bounds__(256) void scores_nt(const __half* __restrict__ A,
                                                 const float* __restrict__ ws,
                                                 const float* __restrict__ wd,
                                                 float* __restrict__ es,
                                                 float* __restrict__ ed, int N) {
    int n = blockIdx.x * blockDim.x + threadIdx.x;
    if (n >= N) return;
    const __half* row = A + (size_t)n * K;
    float s[H] = {}, d[H] = {};
#pragma unroll
    for (int k0 = 0; k0 < K; k0 += 8) {
        uint4 raw = *(const uint4*)(row + k0);
        const __half* hv = (const __half*)&raw;
        float a[8];
#pragma unroll
        for (int q = 0; q < 8; ++q) a[q] = __half2float(hv[q]);
#pragma unroll
        for (int h = 0; h < H; ++h)
#pragma unroll
            for (int q = 0; q < 8; ++q) {
                s[h] += a[q] * ws[h * K + k0 + q];
                d[h] += a[q] * wd[h * K + k0 + q];
            }
    }
#pragma unroll
    for (int h = 0; h < H; ++h) {
        es[(size_t)n * H + h] = s[h];
        ed[(size_t)n * H + h] = d[h];
    }
}

// ------- FUSED softmax + aggregation, 8-edge chunked (enc0, H=8 C=64) ----
// NO extra epilogue: keeps VGPR=48 / occupancy ~41% (R15 fusion caused a cliff).
template <bool RELU>
__global__ __launch_bounds__(256) void gat_gather_h8(const __half* __restrict__ hsrc,
                                                     const float* __restrict__ es,
                                                     const float* __restrict__ ed,
                                                     const int* __restrict__ off,
                                                     const int* __restrict__ esrc,
                                                     const float* __restrict__ bias,
                                                     __half* __restrict__ out, int N) {
    constexpr int HC = 512;
    int n = (blockIdx.x * blockDim.x + threadIdx.x) >> 6;
    int lane = threadIdx.x & 63;
    if (n >= N) return;
    int hd = lane >> 3;
    int k8 = lane >> 3, h8 = lane & 7;
    int j0 = off[n], j1 = off[n + 1];

    float edl = ed[(size_t)n * 8 + h8];

    float acc[8] = {};
    float denacc = 0.f;
    for (int j = j0; j < j1; j += 8) {
        int jj = j + k8;
        int jc = (jj < j1) ? jj : (j1 - 1);
        int sidx = esrc[jc];
        float v = es[(size_t)sidx * 8 + h8] + edl;
        v = (v > 0.f) ? v : 0.2f * v;
        float pm = (jj < j1) ? expf(v) : 0.f;
        denacc += pm;
        uint4 rw[8];
#pragma unroll
        for (int k = 0; k < 8; ++k) {
            int sb = __shfl(sidx, k * 8);
            rw[k] = *(const uint4*)(hsrc + (size_t)sb * HC + 8 * lane);
        }
#pragma unroll
        for (int k = 0; k < 8; ++k) {
            float a = __shfl(pm, k * 8 + hd);
            const __half* hv = (const __half*)&rw[k];
#pragma unroll
            for (int q = 0; q < 8; ++q) acc[q] += a * __half2float(hv[q]);
        }
    }

    float den = denacc;
#pragma unroll
    for (int o = 8; o < 64; o <<= 1) den += __shfl_xor(den, o);
    float dv = __shfl(den, hd) + 1e-16f;

#pragma unroll
    for (int q = 0; q < 8; ++q) acc[q] /= dv;
#pragma unroll
    for (int o = 8; o < 64; o <<= 1)
#pragma unroll
        for (int q = 0; q < 8; ++q) acc[q] += __shfl_xor(acc[q], o);

    if (lane < 8) {
        int cbase = 8 * lane;
        float r[8];
#pragma unroll
        for (int q = 0; q < 8; ++q) {
            float o2 = acc[q] * 0.125f + bias[cbase + q];
            if (RELU) o2 = fmaxf(o2, 0.f);
            r[q] = o2;
        }
        __half2 p0 = __floats2half2_rn(r[0], r[1]);
        __half2 p1 = __floats2half2_rn(r[2], r[3]);
        __half2 p2 = __floats2half2_rn(r[4], r[5]);
        __half2 p3 = __floats2half2_rn(r[6], r[7]);
        uint4 pk;
        pk.x = *(unsigned*)&p0; pk.y = *(unsigned*)&p1;
        pk.z = *(unsigned*)&p2; pk.w = *(unsigned*)&p3;
        *(uint4*)(out + (size_t)n * 64 + cbase) = pk;
    }
}

// ------- enc1 z-gather: lane=(head h, slice q); zero shuffles ---------------
__global__ __launch_bounds__(256) void gat_gather_zh8(const __half* __restrict__ A,
                                                      const float* __restrict__ es,
                                                      const float* __restrict__ ed,
                                                      const int* __restrict__ off,
                                                      const int* __restrict__ esrc,
                                                      __half* __restrict__ z, int N) {
    int n = (blockIdx.x * blockDim.x + threadIdx.x) >> 6;
    int lane = threadIdx.x & 63;
    if (n >= N) return;
    int h = lane >> 3, q = lane & 7;
    int j0 = off[n], j1 = off[n + 1];
    float edv = ed[(size_t)n * 8 + h];

    float acc[8] = {};
    float den = 0.f;
    int j = j0;
    for (; j + 1 < j1; j += 2) {
        int s0 = esrc[j], s1 = esrc[j + 1];
        float v0 = es[(size_t)s0 * 8 + h] + edv;
        float v1 = es[(size_t)s1 * 8 + h] + edv;
        v0 = (v0 > 0.f) ? v0 : 0.2f * v0;
        v1 = (v1 > 0.f) ? v1 : 0.2f * v1;
        float p0 = expf(v0), p1 = expf(v1);
        den += p0 + p1;
        uint4 r0 = *(const uint4*)(A + (size_t)s0 * 64 + 8 * q);
        uint4 r1 = *(const uint4*)(A + (size_t)s1 * 64 + 8 * q);
        const __half* h0 = (const __half*)&r0;
        const __half* h1 = (const __half*)&r1;
#pragma unroll
        for (int k = 0; k < 8; ++k)
            acc[k] += p0 * __half2float(h0[k]) + p1 * __half2float(h1[k]);
    }
    if (j < j1) {
        int s0 = esrc[j];
        float v0 = es[(size_t)s0 * 8 + h] + edv;
        v0 = (v0 > 0.f) ? v0 : 0.2f * v0;
        float p0 = expf(v0);
        den += p0;
        uint4 r0 = *(const uint4*)(A + (size_t)s0 * 64 + 8 * q);
        const __half* h0 = (const __half*)&r0;
#pragma unroll
        for (int k = 0; k < 8; ++k) acc[k] += p0 * __half2float(h0[k]);
    }

    float inv = 1.f / ((den + 1e-16f) * 8.f);
    float r[8];
#pragma unroll
    for (int k = 0; k < 8; ++k) r[k] = acc[k] * inv;
    __half2 p0 = __floats2half2_rn(r[0], r[1]);
    __half2 p1 = __floats2half2_rn(r[2], r[3]);
    __half2 p2 = __floats2half2_rn(r[4], r[5]);
    __half2 p3 = __floats2half2_rn(r[6], r[7]);
    uint4 pk;
    pk.x = *(unsigned*)&p0; pk.y = *(unsigned*)&p1;
    pk.z = *(unsigned*)&p2; pk.w = *(unsigned*)&p3;
    *(uint4*)(z + (size_t)n * 512 + h * 64 + 8 * q) = pk;
}

// -------- dec1 z-gather, 8-edge chunked ----------------
__global__ __launch_bounds__(256) void gat_gather_z8(const __half* __restrict__ A,
                                                     const float* __restrict__ es,
                                                     const float* __restrict__ ed,
                                                     const int* __restrict__ off,
                                                     const int* __restrict__ esrc,
                                                     __half* __restrict__ z, int N) {
    int n = (blockIdx.x * blockDim.x + threadIdx.x) >> 6;
    int lane = threadIdx.x & 63;
    if (n >= N) return;
    int k8 = lane >> 3, q8 = lane & 7;
    int j0 = off[n], j1 = off[n + 1];
    float edv = ed[n];

    float acc[8] = {};
    float denacc = 0.f;
    for (int j = j0; j < j1; j += 8) {
        int jj = j + k8;
        int jc = (jj < j1) ? jj : (j1 - 1);
        int sidx = esrc[jc];
        float v = es[sidx] + edv;
        v = (v > 0.f) ? v : 0.2f * v;
        float pm = (jj < j1) ? expf(v) : 0.f;
        denacc += pm;
        uint4 rw = *(const uint4*)(A + (size_t)sidx * 64 + 8 * q8);
        const __half* hv = (const __half*)&rw;
#pragma unroll
        for (int q = 0; q < 8; ++q) acc[q] += pm * __half2float(hv[q]);
    }

    float den = denacc;
#pragma unroll
    for (int o = 8; o < 64; o <<= 1) {
        den += __shfl_xor(den, o);
#pragma unroll
        for (int q = 0; q < 8; ++q) acc[q] += __shfl_xor(acc[q], o);
    }
    float inv = 1.f / (den + 1e-16f);
    if (lane < 8) {
        float r[8];
#pragma unroll
        for (int q = 0; q < 8; ++q) r[q] = acc[q] * inv;
        __half2 p0 = __floats2half2_rn(r[0], r[1]);
        __half2 p1 = __floats2half2_rn(r[2], r[3]);
        __half2 p2 = __floats2half2_rn(r[4], r[5]);
        __half2 p3 = __floats2half2_rn(r[6], r[7]);
        uint4 pk;
        pk.x = *(unsigned*)&p0; pk.y = *(unsigned*)&p1;
        pk.z = *(unsigned*)&p2; pk.w = *(unsigned*)&p3;
        *(uint4*)(z + (size_t)n * 64 + 8 * lane) = pk;
    }
}

// ---------------- K-tiled MFMA GEMM with bias/relu (z-path) ------------------
template <int KK, typename OUTT, bool RELU>
__global__ __launch_bounds__(256) void gemm_kt(const __half* __restrict__ A,
                                               const __half* __restrict__ BT,
                                               const float* __restrict__ bias,
                                               OUTT* __restrict__ C,
                                               int M, int Nout) {
    __shared__ __align__(16) __half As[64 * 72];
    __shared__ __align__(16) __half Bs[64 * 72];
    int tid = threadIdx.x;
    int bm = blockIdx.y * 64, bn = blockIdx.x * 64;
    int wv = tid >> 6, l = tid & 63, lr = l & 15, g = l >> 4;
    float4v acc[4] = {{0.f, 0.f, 0.f, 0.f}, {0.f, 0.f, 0.f, 0.f},
                      {0.f, 0.f, 0.f, 0.f}, {0.f, 0.f, 0.f, 0.f}};
    for (int kc = 0; kc < KK; kc += 64) {
        __syncthreads();
        for (int idx = tid; idx < 512; idx += 256) {
            int row = idx >> 3, ko = (idx & 7) * 8;
            uint4 v = make_uint4(0u, 0u, 0u, 0u);
            int gr = bm + row;
            if (gr < M) v = *(const uint4*)(A + (size_t)gr * KK + kc + ko);
            *(uint4*)(&As[row * 72 + ko]) = v;
            uint4 wvv = *(const uint4*)(BT + (size_t)(bn + row) * KK + kc + ko);
            *(uint4*)(&Bs[row * 72 + ko]) = wvv;
        }
        __syncthreads();
#pragma unroll
        for (int k0 = 0; k0 < 64; k0 += 32) {
            half8v af = *reinterpret_cast<const half8v*>(&As[(16 * wv + lr) * 72 + k0 + 8 * g]);
#pragma unroll
            for (int nt = 0; nt < 4; ++nt) {
                half8v bf = *reinterpret_cast<const half8v*>(&Bs[(nt * 16 + lr) * 72 + k0 + 8 * g]);
                acc[nt] = __builtin_amdgcn_mfma_f32_16x16x32_f16(af, bf, acc[nt], 0, 0, 0);
            }
        }
    }
#pragma unroll
    for (int nt = 0; nt < 4; ++nt) {
        float b = bias[bn + nt * 16 + lr];
#pragma unroll
        for (int r = 0; r < 4; ++r) {
            int grow = bm + 16 * wv + 4 * g + r;
            if (grow < M) {
                float c = acc[nt][r] + b;
                if (RELU) c = fmaxf(c, 0.f);
                if constexpr (sizeof(OUTT) == 2)
                    C[(size_t)grow * Nout + bn + nt * 16 + lr] = __float2half(c);
                else
                    C[(size_t)grow * Nout + bn + nt * 16 + lr] = c;
            }
        }
    }
}

// ------- dec0 gather (8-edge chunked) + FUSED dec1 scores (H=1, cheap) -------
__global__ __launch_bounds__(256) void gat_gather_d08s(const float* __restrict__ hsrc,
                                                       const float* __restrict__ es16,
                                                       const float* __restrict__ ed16,
                                                       const int* __restrict__ off,
                                                       const int* __restrict__ esrc,
                                                       const int* __restrict__ batch,
                                                       const float* __restrict__ bias,
                                                       const float* __restrict__ ws2,
                                                       const float* __restrict__ wd2,
                                                       __half* __restrict__ out,
                                                       float* __restrict__ es2,
                                                       float* __restrict__ ed2, int N) {
    int n = (blockIdx.x * blockDim.x + threadIdx.x) >> 6;
    int lane = threadIdx.x & 63;
    if (n >= N) return;
    int k8 = lane >> 3, q8 = lane & 7;
    int j0 = off[n], j1 = off[n + 1];
    float edv = ed16[batch[n]];

    float acc[8] = {};
    float denacc = 0.f;
    for (int j = j0; j < j1; j += 8) {
        int jj = j + k8;
        int jc = (jj < j1) ? jj : (j1 - 1);
        int g = batch[esrc[jc]];
        float v = es16[g] + edv;
        v = (v > 0.f) ? v : 0.2f * v;
        float pm = (jj < j1) ? expf(v) : 0.f;
        denacc += pm;
        const float* row = hsrc + (size_t)g * 64 + 8 * q8;
        float4 r0 = *(const float4*)row;
        float4 r1 = *(const float4*)(row + 4);
        acc[0] += pm * r0.x; acc[1] += pm * r0.y;
        acc[2] += pm * r0.z; acc[3] += pm * r0.w;
        acc[4] += pm * r1.x; acc[5] += pm * r1.y;
        acc[6] += pm * r1.z; acc[7] += pm * r1.w;
    }

    float den = denacc;
#pragma unroll
    for (int o = 8; o < 64; o <<= 1) {
        den += __shfl_xor(den, o);
#pragma unroll
        for (int q = 0; q < 8; ++q) acc[q] += __shfl_xor(acc[q], o);
    }
    float inv = 1.f / (den + 1e-16f);
    if (lane < 8) {
        int cbase = 8 * lane;
        float r[8];
#pragma unroll
        for (int q = 0; q < 8; ++q) r[q] = fmaxf(acc[q] * inv + bias[cbase + q], 0.f);
        __half2 p0 = __floats2half2_rn(r[0], r[1]);
        __half2 p1 = __floats2half2_rn(r[2], r[3]);
        __half2 p2 = __floats2half2_rn(r[4], r[5]);
        __half2 p3 = __floats2half2_rn(r[6], r[7]);
        uint4 pk;
        pk.x = *(unsigned*)&p0; pk.y = *(unsigned*)&p1;
        pk.z = *(unsigned*)&p2; pk.w = *(unsigned*)&p3;
        *(uint4*)(out + (size_t)n * 64 + cbase) = pk;
        // fused dec1 scores (H=1)
        float ps = 0.f, pd = 0.f;
#pragma unroll
        for (int q = 0; q < 8; ++q) {
            ps += r[q] * ws2[cbase + q];
            pd += r[q] * wd2[cbase + q];
        }
#pragma unroll
        for (int o = 1; o < 8; o <<= 1) {
            ps += __shfl_xor(ps, o);
            pd += __shfl_xor(pd, o);
        }
        if (lane == 0) {
            es2[n] = ps;
            ed2[n] = pd;
        }
    }
}

// ---- gate via MFMA + FUSED pooled sum (bufB tile already in LDS) ------------
__global__ __launch_bounds__(256) void gate_pool_mfma(const __half* __restrict__ A,
                                                      const __half* __restrict__ BT,
                                                      const float* __restrict__ b1,
                                                      const float* __restrict__ w2,
                                                      const float* __restrict__ b2,
                                                      const int* __restrict__ batch,
                                                      float* __restrict__ pg,
                                                      float* __restrict__ gden,
                                                      float* __restrict__ pooled, int M) {
    constexpr int KP = 72;
    __shared__ __align__(16) __half As[64 * KP];
    __shared__ __align__(16) __half Bs[64 * KP];
    __shared__ float part[16];
    __shared__ float sp[64];
    __shared__ int sb[64];
    int tid = threadIdx.x;
    if (tid < 16) part[tid] = 0.f;
    int bm = blockIdx.x * 64;
    for (int idx = tid; idx < 512; idx += 256) {
        int row = idx >> 3, ko = (idx & 7) * 8;
        uint4 v = make_uint4(0u, 0u, 0u, 0u);
        int gr = bm + row;
        if (gr < M) v = *(const uint4*)(A + (size_t)gr * 64 + ko);
        *(uint4*)(&As[row * KP + ko]) = v;
        uint4 wvv = *(const uint4*)(BT + (size_t)row * 64 + ko);
        *(uint4*)(&Bs[row * KP + ko]) = wvv;
    }
    __syncthreads();
    int wv_ = tid >> 6, l = tid & 63;
    int lr = l & 15, g = l >> 4;
    float4v acc[4] = {{0.f, 0.f, 0.f, 0.f}, {0.f, 0.f, 0.f, 0.f},
                      {0.f, 0.f, 0.f, 0.f}, {0.f, 0.f, 0.f, 0.f}};
    const __half* ap = &As[(16 * wv_ + lr) * KP + 8 * g];
    const __half* bp = &Bs[lr * KP + 8 * g];
#pragma unroll
    for (int k0 = 0; k0 < 64; k0 += 32) {
        half8v af = *reinterpret_cast<const half8v*>(ap + k0);
#pragma unroll
        for (int nt = 0; nt < 4; ++nt) {
            half8v bf = *reinterpret_cast<const half8v*>(bp + nt * 16 * KP + k0);
            acc[nt] = __builtin_amdgcn_mfma_f32_16x16x32_f16(af, bf, acc[nt], 0, 0, 0);
        }
    }
    float partial[4];
#pragma unroll
    for (int r = 0; r < 4; ++r) {
        float t = 0.f;
#pragma unroll
        for (int nt = 0; nt < 4; ++nt) {
            int col = nt * 16 + lr;
            float tv = acc[nt][r] + b1[col];
            tv = fmaxf(tv, 0.f);
            t += tv * w2[col];
        }
        partial[r] = t;
    }
#pragma unroll
    for (int o = 1; o < 16; o <<= 1)
#pragma unroll
        for (int r = 0; r < 4; ++r) partial[r] += __shfl_xor(partial[r], o);
    if (lr == 0) {
        float bb = b2[0];
#pragma unroll
        for (int r = 0; r < 4; ++r) {
            int row = 16 * wv_ + 4 * g + r;
            int grow = bm + row;
            if (grow < M) {
                float p = expf(partial[r] + bb);
                pg[grow] = p;
                int bg = batch[grow];
                sp[row] = p;
                sb[row] = bg;
                atomicAdd(&part[bg], p);
            }
        }
    }
    __syncthreads();
    if (tid < 16 && part[tid] != 0.f) atomicAdd(&gden[tid], part[tid]);
    if (tid < 64) {
        int nrows = min(64, M - bm);
        int curg = sb[0];
        float acc2 = 0.f;
        for (int row = 0; row < nrows; ++row) {
            int g2 = sb[row];
            if (g2 != curg) {
                atomicAdd(&pooled[curg * 64 + tid], acc2);
                acc2 = 0.f;
                curg = g2;
            }
            acc2 += sp[row] * __half2float(As[row * KP + tid]);
        }
        atomicAdd(&pooled[curg * 64 + tid], acc2);
    }
}

__global__ void dec_prep(const float* __restrict__ pooled, const float* __restrict__ gden,
                         const float* __restrict__ Wd0, const float* __restrict__ asd,
                         const float* __restrict__ add, float* __restrict__ hd016,
                         float* __restrict__ es16, float* __restrict__ ed16) {
    int g = blockIdx.x;
    int lane = threadIdx.x;
    float pn = pooled[g * 64 + lane] / (gden[g] + 1e-16f);
    float o = 0.f;
    for (int c = 0; c < 64; ++c) o += __shfl(pn, c) * Wd0[c * 64 + lane];
    hd016[g * 64 + lane] = o;
    float s = o * asd[lane], d = o * add[lane];
#pragma unroll
    for (int off = 32; off; off >>= 1) {
        s += __shfl_xor(s, off);
        d += __shfl_xor(d, off);
    }
    if (lane == 0) {
        es16[g] = s;
        ed16[g] = d;
    }
}

// ---------------- host ----------------
static inline int cdiv(int a, int b) { return (a + b - 1) / b; }

extern "C" void kernel_launch(void* const* d_in, const int* in_sizes, int n_in,
                              void* d_out, int out_size, void* d_ws, size_t ws_size,
                              hipStream_t stream) {
    const float* x      = (const float*)d_in[0];
    const int*   ei     = (const int*)  d_in[1];
    const int*   batch  = (const int*)  d_in[2];
    const float* W_e0   = (const float*)d_in[3];
    const float* a_s_e0 = (const float*)d_in[4];
    const float* a_d_e0 = (const float*)d_in[5];
    const float* b_e0   = (const float*)d_in[6];
    const float* W_e1   = (const float*)d_in[7];
    const float* a_s_e1 = (const float*)d_in[8];
    const float* a_d_e1 = (const float*)d_in[9];
    const float* b_e1   = (const float*)d_in[10];
    const float* W_d0   = (const float*)d_in[11];
    const float* a_s_d0 = (const float*)d_in[12];
    const float* a_d_d0 = (const float*)d_in[13];
    const float* b_d0   = (const float*)d_in[14];
    const float* W_d1   = (const float*)d_in[15];
    const float* a_s_d1 = (const float*)d_in[16];
    const float* a_d_d1 = (const float*)d_in[17];
    const float* b_d1   = (const float*)d_in[18];
    const float* g_w1   = (const float*)d_in[19];
    const float* g_b1   = (const float*)d_in[20];
    const float* g_w2   = (const float*)d_in[21];
    const float* g_b2   = (const float*)d_in[22];

    const int N    = in_sizes[2];
    const int E    = in_sizes[1] / 2;
    const int Etot = E + N;
    const int Din  = in_sizes[0] / N;  // 128

    char* w = (char*)d_ws;
    size_t o = 0;
    auto alloc = [&](size_t bytes) -> void* {
        void* p = w + o;
        o = (o + bytes + 255) & ~(size_t)255;
        return p;
    };
    __half*   h16    = (__half*)  alloc((size_t)N * 512 * 2);  // enc0 h / enc1 z / dec1 z
    __half*   x16    = (__half*)  alloc((size_t)N * Din * 2);
    __half*   bufA   = (__half*)  alloc((size_t)N * 64 * 2);
    __half*   bufB   = (__half*)  alloc((size_t)N * 64 * 2);
    __half*   wt_e0  = (__half*)  alloc((size_t)512 * 128 * 2);
    __half*   wst_e1 = (__half*)  alloc((size_t)64 * 512 * 2);
    __half*   wst_d1 = (__half*)  alloc((size_t)128 * 64 * 2);
    __half*   wt_g1  = (__half*)  alloc((size_t)64 * 64 * 2);
    float*    ws_e0  = (float*)   alloc(8 * 128 * 4);
    float*    wd_e0  = (float*)   alloc(8 * 128 * 4);
    float*    ws_e1  = (float*)   alloc(8 * 64 * 4);
    float*    wd_e1  = (float*)   alloc(8 * 64 * 4);
    float*    ws_d1  = (float*)   alloc(64 * 4);
    float*    wd_d1  = (float*)   alloc(64 * 4);
    float*    es     = (float*)   alloc((size_t)N * 8 * 4);
    float*    ed     = (float*)   alloc((size_t)N * 8 * 4);
    float*    pg     = (float*)   alloc((size_t)N * 4);
    int*      off    = (int*)     alloc((size_t)(N + 1) * 4);
    int*      cnt    = (int*)     alloc((size_t)N * 4);
    int*      esrc   = (int*)     alloc((size_t)Etot * 4);
    int*      bsum   = (int*)     alloc(256 * 4);
    float*    gden   = (float*)   alloc(16 * 4);      // gden+pooled adjacent:
    float*    pooled = (float*)   alloc(16 * 64 * 4); // one memset covers both
    float*    hd016  = (float*)   alloc(16 * 64 * 4);
    float*    es16   = (float*)   alloc(16 * 4);
    float*    ed16   = (float*)   alloc(16 * 4);
    (void)ws_size; (void)n_in; (void)out_size;

    const int nodeWaveGrid = cdiv(N, 4);
    const int nodeThreadGrid = cdiv(N, TB);
    const int edgeGrid     = cdiv(Etot, TB);
    const int scanBlocks   = cdiv(N, 256);

    // ---- CSR ----
    hipMemsetAsync(cnt, 0, (size_t)N * 4, stream);
    csr_count<<<edgeGrid, TB, 0, stream>>>(ei, E, Etot, cnt);
    scan_phase1<<<scanBlocks, 256, 0, stream>>>(cnt, esrc /*temp incl*/, bsum, N);
    scan_phase2<<<1, 256, 0, stream>>>(bsum, scanBlocks);
    scan_phase3<<<scanBlocks, 256, 0, stream>>>(esrc, bsum, off, N);
    hipMemsetAsync(cnt, 0, (size_t)N * 4, stream);
    csr_fill<<<edgeGrid, TB, 0, stream>>>(ei, E, Etot, off, cnt, esrc);

    // ---- merged prep ----
    prep_weights<<<cdiv(110592, TB), TB, 0, stream>>>(W_e0, g_w1, W_e1, W_d1,
                                                      wt_e0, wt_g1, wst_e1, wst_d1);
    prep_ws<<<cdiv(1600, TB), TB, 0, stream>>>(W_e0, a_s_e0, a_d_e0,
                                               W_e1, a_s_e1, a_d_e1,
                                               W_d1, a_s_d1, a_d_d1,
                                               ws_e0, wd_e0, ws_e1, wd_e1, ws_d1, wd_d1);

    // ---- encoder layer 0 (H=8, relu) ----
    scores_cast_nt<128, 8><<<nodeThreadGrid, TB, 0, stream>>>(x, x16, ws_e0, wd_e0, es, ed, N);
    {
        dim3 grid(512 / 128, cdiv(N, 64));
        gemm_mfma_wide<<<grid, TB, 0, stream>>>(x16, wt_e0, h16, N, 512);
    }
    gat_gather_h8<true><<<nodeWaveGrid, TB, 0, stream>>>(
        h16, es, ed, off, esrc, b_e0, bufA, N);

    // ---- encoder layer 1 (H=8, no relu): z-path ----
    scores_nt<64, 8><<<nodeThreadGrid, TB, 0, stream>>>(bufA, ws_e1, wd_e1, es, ed, N);
    gat_gather_zh8<<<nodeWaveGrid, TB, 0, stream>>>(bufA, es, ed, off, esrc, h16 /*z*/, N);
    {
        dim3 grid(1, cdiv(N, 64));
        gemm_kt<512, __half, false><<<grid, TB, 0, stream>>>(h16 /*z*/, wst_e1, b_e1, bufB, N, 64);
    }

    // ---- pooling (gate + pooled sum fused) ----
    hipMemsetAsync(gden, 0, 256 + 16 * 64 * 4, stream);
    gate_pool_mfma<<<cdiv(N, 64), TB, 0, stream>>>(bufB, wt_g1, g_b1, g_w2, g_b2,
                                                   batch, pg, gden, pooled, N);
    dec_prep<<<16, 64, 0, stream>>>(pooled, gden, W_d0, a_s_d0, a_d_d0, hd016, es16, ed16);

    // ---- decoder layer 0 (H=1, relu) + fused dec1 scores ----
    gat_gather_d08s<<<nodeWaveGrid, TB, 0, stream>>>(
        hd016, es16, ed16, off, esrc, batch, b_d0, ws_d1, wd_d1, bufA, es, ed, N);

    // ---- decoder layer 1 (H=1, C=128, no relu): z-path -> d_out ----
    gat_gather_z8<<<nodeWaveGrid, TB, 0, stream>>>(bufA, es, ed, off, esrc, h16 /*z*/, N);
    {
        dim3 grid(2, cdiv(N, 64));
        gemm_kt<64, float, false><<<grid, TB, 0, stream>>>(h16 /*z*/, wst_d1, b_d1, (float*)d_out, N, 128);
    }
}

// Round 18
// 322.734 us; speedup vs baseline: 1.1443x; 1.0146x over previous
//
#include <hip/hip_runtime.h>
#include <hip/hip_fp16.h>
#include <math.h>

#define TB 256

typedef _Float16 half8v __attribute__((ext_vector_type(8)));
typedef float float4v __attribute__((ext_vector_type(4)));

static __device__ __forceinline__ int edge_src(const int* ei, int E, int e) {
    return (e < E) ? ei[e] : (e - E);
}
static __device__ __forceinline__ int edge_dst(const int* ei, int E, int e) {
    return (e < E) ? ei[E + e] : (e - E);
}

// ---------------- CSR build ----------------
__global__ void csr_count(const int* __restrict__ ei, int E, int Etot, int* __restrict__ cnt) {
    int e = blockIdx.x * blockDim.x + threadIdx.x;
    if (e >= Etot) return;
    atomicAdd(&cnt[edge_dst(ei, E, e)], 1);
}

__global__ __launch_bounds__(256) void scan_phase1(const int* __restrict__ cnt,
                                                   int* __restrict__ incl,
                                                   int* __restrict__ bsum, int n) {
    __shared__ int sdata[256];
    int t = threadIdx.x;
    int base = blockIdx.x * 256;
    int v = (base + t < n) ? cnt[base + t] : 0;
    for (int d = 1; d < 256; d <<= 1) {
        sdata[t] = v; __syncthreads();
        if (t >= d) v += sdata[t - d];
        __syncthreads();
    }
    if (base + t < n) incl[base + t] = v;
    if (t == 255) bsum[blockIdx.x] = v;
}

__global__ void scan_phase2(int* bsum, int nb) {
    __shared__ int sdata[256];
    int t = threadIdx.x;
    int v = (t < nb) ? bsum[t] : 0;
    for (int d = 1; d < 256; d <<= 1) {
        sdata[t] = v; __syncthreads();
        if (t >= d) v += sdata[t - d];
        __syncthreads();
    }
    if (t < nb) bsum[t] = v;
}

__global__ __launch_bounds__(256) void scan_phase3(const int* __restrict__ incl,
                                                   const int* __restrict__ bsum,
                                                   int* __restrict__ off, int n) {
    int i = blockIdx.x * 256 + threadIdx.x;
    if (i < n) off[i + 1] = incl[i] + (blockIdx.x ? bsum[blockIdx.x - 1] : 0);
    if (i == 0) off[0] = 0;
}

__global__ void csr_fill(const int* __restrict__ ei, int E, int Etot,
                         const int* __restrict__ off, int* __restrict__ cur,
                         int* __restrict__ esrc) {
    int e = blockIdx.x * blockDim.x + threadIdx.x;
    if (e >= Etot) return;
    int d = edge_dst(ei, E, e);
    int pos = atomicAdd(&cur[d], 1);
    esrc[off[d] + pos] = edge_src(ei, E, e);
}

// ------ merged weight prep (all transposes/stacks + folded ws in ONE launch) -
__global__ void prep_all(const float* __restrict__ W_e0, const float* __restrict__ g_w1,
                         const float* __restrict__ W_e1, const float* __restrict__ W_d1,
                         const float* __restrict__ a_s_e0, const float* __restrict__ a_d_e0,
                         const float* __restrict__ a_s_e1, const float* __restrict__ a_d_e1,
                         const float* __restrict__ a_s_d1, const float* __restrict__ a_d_d1,
                         __half* __restrict__ wt_e0, __half* __restrict__ wt_g1,
                         __half* __restrict__ wst_e1, __half* __restrict__ wst_d1,
                         float* __restrict__ ws_e0, float* __restrict__ wd_e0,
                         float* __restrict__ ws_e1, float* __restrict__ wd_e1,
                         float* __restrict__ ws_d1, float* __restrict__ wd_d1) {
    int i = blockIdx.x * blockDim.x + threadIdx.x;
    if (i < 65536) {
        int nn = i / 128, kk = i % 128;
        wt_e0[i] = __float2half(W_e0[kk * 512 + nn]);
    } else if (i < 69632) {
        int j = i - 65536;
        int nn = j / 64, kk = j % 64;
        wt_g1[j] = __float2half(g_w1[kk * 64 + nn]);
    } else if (i < 102400) {
        int j = i - 69632;
        int c = j / 512, rem = j % 512;
        int h = rem / 64, k = rem % 64;
        wst_e1[j] = __float2half(W_e1[(size_t)k * 512 + h * 64 + c]);
    } else if (i < 110592) {
        int j = i - 102400;
        int c = j / 64, k = j % 64;
        wst_d1[j] = __float2half(W_d1[(size_t)k * 128 + c]);
    } else if (i < 112192) {
        int jj = i - 110592;
        const float* W; const float* as_; const float* ad_;
        float* ws; float* wd;
        int K, H, C, j;
        if (jj < 1024) { j = jj; K = 128; H = 8; C = 64; W = W_e0; as_ = a_s_e0; ad_ = a_d_e0; ws = ws_e0; wd = wd_e0; }
        else if (jj < 1536) { j = jj - 1024; K = 64; H = 8; C = 64; W = W_e1; as_ = a_s_e1; ad_ = a_d_e1; ws = ws_e1; wd = wd_e1; }
        else { j = jj - 1536; K = 64; H = 1; C = 128; W = W_d1; as_ = a_s_d1; ad_ = a_d_d1; ws = ws_d1; wd = wd_d1; }
        int h = j / K, k = j % K;
        const float* wrow = W + (size_t)k * H * C + h * C;
        float s = 0.f, d = 0.f;
        for (int c = 0; c < C; ++c) {
            s += wrow[c] * as_[h * C + c];
            d += wrow[c] * ad_[h * C + c];
        }
        ws[j] = s;
        wd[j] = d;
    }
}

// --- wide MFMA GEMM for enc0, SELF-CASTING fp32 A: BM=64, BN=128, K=128 -----
__global__ __launch_bounds__(256) void gemm_mfma_wide_f32(const float* __restrict__ A,
                                                          const __half* __restrict__ BT,
                                                          __half* __restrict__ C,
                                                          int M, int N) {
    constexpr int K = 128, KP = 136;
    __shared__ __align__(16) __half As[64 * KP];
    __shared__ __align__(16) __half Bs[128 * KP];
    int tid = threadIdx.x;
    int bm = blockIdx.y * 64, bn = blockIdx.x * 128;
    for (int idx = tid; idx < 64 * 16; idx += 256) {
        int row = idx >> 4, ko = (idx & 15) * 8;
        int gr = bm + row;
        uint4 pk = make_uint4(0u, 0u, 0u, 0u);
        if (gr < M) {
            float4 a0 = *(const float4*)(A + (size_t)gr * K + ko);
            float4 a1 = *(const float4*)(A + (size_t)gr * K + ko + 4);
            __half2 h0 = __floats2half2_rn(a0.x, a0.y);
            __half2 h1 = __floats2half2_rn(a0.z, a0.w);
            __half2 h2 = __floats2half2_rn(a1.x, a1.y);
            __half2 h3 = __floats2half2_rn(a1.z, a1.w);
            pk.x = *(unsigned*)&h0; pk.y = *(unsigned*)&h1;
            pk.z = *(unsigned*)&h2; pk.w = *(unsigned*)&h3;
        }
        *(uint4*)(&As[row * KP + ko]) = pk;
    }
    for (int idx = tid; idx < 128 * 16; idx += 256) {
        int row = idx >> 4, ko = (idx & 15) * 8;
        *(uint4*)(&Bs[row * KP + ko]) = *(const uint4*)(BT + (size_t)(bn + row) * K + ko);
    }
    __syncthreads();
    int wv_ = tid >> 6, l = tid & 63;
    int lr = l & 15, g = l >> 4;
    float4v acc[8] = {{0,0,0,0},{0,0,0,0},{0,0,0,0},{0,0,0,0},
                      {0,0,0,0},{0,0,0,0},{0,0,0,0},{0,0,0,0}};
    const __half* ap = &As[(16 * wv_ + lr) * KP + 8 * g];
    const __half* bp = &Bs[lr * KP + 8 * g];
#pragma unroll
    for (int k0 = 0; k0 < K; k0 += 32) {
        half8v af = *reinterpret_cast<const half8v*>(ap + k0);
#pragma unroll
        for (int nt = 0; nt < 8; ++nt) {
            half8v bf = *reinterpret_cast<const half8v*>(bp + nt * 16 * KP + k0);
            acc[nt] = __builtin_amdgcn_mfma_f32_16x16x32_f16(af, bf, acc[nt], 0, 0, 0);
        }
    }
#pragma unroll
    for (int nt = 0; nt < 8; ++nt) {
#pragma unroll
        for (int r = 0; r < 4; ++r) {
            int grow = bm + 16 * wv_ + 4 * g + r;
            if (grow < M)
                C[(size_t)grow * N + bn + nt * 16 + lr] = __float2half(acc[nt][r]);
        }
    }
}

// ------- enc0 scores from fp32 x, thread-per-node --------
template <int K, int H>
__global__ __launch_bounds__(256) void scores_f32(const float* __restrict__ X,
                                                  const float* __restrict__ ws,
                                                  const float* __restrict__ wd,
                                                  float* __restrict__ es,
                                                  float* __restrict__ ed, int N) {
    int n = blockIdx.x * blockDim.x + threadIdx.x;
    if (n >= N) return;
    const float* row = X + (size_t)n * K;
    float s[H] = {}, d[H] = {};
#pragma unroll
    for (int k0 = 0; k0 < K; k0 += 8) {
        float4 a0 = *(const float4*)(row + k0);
        float4 a1 = *(const float4*)(row + k0 + 4);
        float a[8] = {a0.x, a0.y, a0.z, a0.w, a1.x, a1.y, a1.z, a1.w};
#pragma unroll
        for (int h = 0; h < H; ++h)
#pragma unroll
            for (int q = 0; q < 8; ++q) {
                s[h] += a[q] * ws[h * K + k0 + q];
                d[h] += a[q] * wd[h * K + k0 + q];
            }
    }
#pragma unroll
    for (int h = 0; h < H; ++h) {
        es[(size_t)n * H + h] = s[h];
        ed[(size_t)n * H + h] = d[h];
    }
}

// ------- scores, thread-per-node (fp16 input) ------
template <int K, int H>
__global__ __launch_bounds__(256) void scores_nt(const __half* __restrict__ A,
                                                 const float* __restrict__ ws,
                                                 const float* __restrict__ wd,
                                                 float* __restrict__ es,
                                                 float* __restrict__ ed, int N) {
    int n = blockIdx.x * blockDim.x + threadIdx.x;
    if (n >= N) return;
    const __half* row = A + (size_t)n * K;
    float s[H] = {}, d[H] = {};
#pragma unroll
    for (int k0 = 0; k0 < K; k0 += 8) {
        uint4 raw = *(const uint4*)(row + k0);
        const __half* hv = (const __half*)&raw;
        float a[8];
#pragma unroll
        for (int q = 0; q < 8; ++q) a[q] = __half2float(hv[q]);
#pragma unroll
        for (int h = 0; h < H; ++h)
#pragma unroll
            for (int q = 0; q < 8; ++q) {
                s[h] += a[q] * ws[h * K + k0 + q];
                d[h] += a[q] * wd[h * K + k0 + q];
            }
    }
#pragma unroll
    for (int h = 0; h < H; ++h) {
        es[(size_t)n * H + h] = s[h];
        ed[(size_t)n * H + h] = d[h];
    }
}

// ------- enc0 gather, 8-edge chunked, PERSISTENT WAVES (grid-stride) ---------
template <bool RELU>
__global__ __launch_bounds__(256) void gat_gather_h8(const __half* __restrict__ hsrc,
                                                     const float* __restrict__ es,
                                                     const float* __restrict__ ed,
                                                     const int* __restrict__ off,
                                                     const int* __restrict__ esrc,
                                                     const float* __restrict__ bias,
                                                     __half* __restrict__ out, int N) {
    constexpr int HC = 512;
    int wid = (blockIdx.x * blockDim.x + threadIdx.x) >> 6;
    int nw = (gridDim.x * blockDim.x) >> 6;
    int lane = threadIdx.x & 63;
    int hd = lane >> 3;
    int k8 = lane >> 3, h8 = lane & 7;

    for (int n = wid; n < N; n += nw) {
        int j0 = off[n], j1 = off[n + 1];
        float edl = ed[(size_t)n * 8 + h8];
        float acc[8] = {};
        float denacc = 0.f;
        for (int j = j0; j < j1; j += 8) {
            int jj = j + k8;
            int jc = (jj < j1) ? jj : (j1 - 1);
            int sidx = esrc[jc];
            float v = es[(size_t)sidx * 8 + h8] + edl;
            v = (v > 0.f) ? v : 0.2f * v;
            float pm = (jj < j1) ? expf(v) : 0.f;
            denacc += pm;
            uint4 rw[8];
#pragma unroll
            for (int k = 0; k < 8; ++k) {
                int sb = __shfl(sidx, k * 8);
                rw[k] = *(const uint4*)(hsrc + (size_t)sb * HC + 8 * lane);
            }
#pragma unroll
            for (int k = 0; k < 8; ++k) {
                float a = __shfl(pm, k * 8 + hd);
                const __half* hv = (const __half*)&rw[k];
#pragma unroll
                for (int q = 0; q < 8; ++q) acc[q] += a * __half2float(hv[q]);
            }
        }

        float den = denacc;
#pragma unroll
        for (int o = 8; o < 64; o <<= 1) den += __shfl_xor(den, o);
        float dv = __shfl(den, hd) + 1e-16f;

#pragma unroll
        for (int q = 0; q < 8; ++q) acc[q] /= dv;
#pragma unroll
        for (int o = 8; o < 64; o <<= 1)
#pragma unroll
            for (int q = 0; q < 8; ++q) acc[q] += __shfl_xor(acc[q], o);

        if (lane < 8) {
            int cbase = 8 * lane;
            float r[8];
#pragma unroll
            for (int q = 0; q < 8; ++q) {
                float o2 = acc[q] * 0.125f + bias[cbase + q];
                if (RELU) o2 = fmaxf(o2, 0.f);
                r[q] = o2;
            }
            __half2 p0 = __floats2half2_rn(r[0], r[1]);
            __half2 p1 = __floats2half2_rn(r[2], r[3]);
            __half2 p2 = __floats2half2_rn(r[4], r[5]);
            __half2 p3 = __floats2half2_rn(r[6], r[7]);
            uint4 pk;
            pk.x = *(unsigned*)&p0; pk.y = *(unsigned*)&p1;
            pk.z = *(unsigned*)&p2; pk.w = *(unsigned*)&p3;
            *(uint4*)(out + (size_t)n * 64 + cbase) = pk;
        }
    }
}

// ------- enc1 z-gather, persistent waves ------------------------------------
__global__ __launch_bounds__(256) void gat_gather_zh8(const __half* __restrict__ A,
                                                      const float* __restrict__ es,
                                                      const float* __restrict__ ed,
                                                      const int* __restrict__ off,
                                                      const int* __restrict__ esrc,
                                                      __half* __restrict__ z, int N) {
    int wid = (blockIdx.x * blockDim.x + threadIdx.x) >> 6;
    int nw = (gridDim.x * blockDim.x) >> 6;
    int lane = threadIdx.x & 63;
    int h = lane >> 3, q = lane & 7;

    for (int n = wid; n < N; n += nw) {
        int j0 = off[n], j1 = off[n + 1];
        float edv = ed[(size_t)n * 8 + h];
        float acc[8] = {};
        float den = 0.f;
        int j = j0;
        for (; j + 1 < j1; j += 2) {
            int s0 = esrc[j], s1 = esrc[j + 1];
            float v0 = es[(size_t)s0 * 8 + h] + edv;
            float v1 = es[(size_t)s1 * 8 + h] + edv;
            v0 = (v0 > 0.f) ? v0 : 0.2f * v0;
            v1 = (v1 > 0.f) ? v1 : 0.2f * v1;
            float p0 = expf(v0), p1 = expf(v1);
            den += p0 + p1;
            uint4 r0 = *(const uint4*)(A + (size_t)s0 * 64 + 8 * q);
            uint4 r1 = *(const uint4*)(A + (size_t)s1 * 64 + 8 * q);
            const __half* h0 = (const __half*)&r0;
            const __half* h1 = (const __half*)&r1;
#pragma unroll
            for (int k = 0; k < 8; ++k)
                acc[k] += p0 * __half2float(h0[k]) + p1 * __half2float(h1[k]);
        }
        if (j < j1) {
            int s0 = esrc[j];
            float v0 = es[(size_t)s0 * 8 + h] + edv;
            v0 = (v0 > 0.f) ? v0 : 0.2f * v0;
            float p0 = expf(v0);
            den += p0;
            uint4 r0 = *(const uint4*)(A + (size_t)s0 * 64 + 8 * q);
            const __half* h0 = (const __half*)&r0;
#pragma unroll
            for (int k = 0; k < 8; ++k) acc[k] += p0 * __half2float(h0[k]);
        }

        float inv = 1.f / ((den + 1e-16f) * 8.f);
        float r[8];
#pragma unroll
        for (int k = 0; k < 8; ++k) r[k] = acc[k] * inv;
        __half2 p0 = __floats2half2_rn(r[0], r[1]);
        __half2 p1 = __floats2half2_rn(r[2], r[3]);
        __half2 p2 = __floats2half2_rn(r[4], r[5]);
        __half2 p3 = __floats2half2_rn(r[6], r[7]);
        uint4 pk;
        pk.x = *(unsigned*)&p0; pk.y = *(unsigned*)&p1;
        pk.z = *(unsigned*)&p2; pk.w = *(unsigned*)&p3;
        *(uint4*)(z + (size_t)n * 512 + h * 64 + 8 * q) = pk;
    }
}

// -------- dec1 z-gather, persistent waves ------------------------------------
__global__ __launch_bounds__(256) void gat_gather_z8(const __half* __restrict__ A,
                                                     const float* __restrict__ es,
                                                     const float* __restrict__ ed,
                                                     const int* __restrict__ off,
                                                     const int* __restrict__ esrc,
                                                     __half* __restrict__ z, int N) {
    int wid = (blockIdx.x * blockDim.x + threadIdx.x) >> 6;
    int nw = (gridDim.x * blockDim.x) >> 6;
    int lane = threadIdx.x & 63;
    int k8 = lane >> 3, q8 = lane & 7;

    for (int n = wid; n < N; n += nw) {
        int j0 = off[n], j1 = off[n + 1];
        float edv = ed[n];
        float acc[8] = {};
        float denacc = 0.f;
        for (int j = j0; j < j1; j += 8) {
            int jj = j + k8;
            int jc = (jj < j1) ? jj : (j1 - 1);
            int sidx = esrc[jc];
            float v = es[sidx] + edv;
            v = (v > 0.f) ? v : 0.2f * v;
            float pm = (jj < j1) ? expf(v) : 0.f;
            denacc += pm;
            uint4 rw = *(const uint4*)(A + (size_t)sidx * 64 + 8 * q8);
            const __half* hv = (const __half*)&rw;
#pragma unroll
            for (int q = 0; q < 8; ++q) acc[q] += pm * __half2float(hv[q]);
        }

        float den = denacc;
#pragma unroll
        for (int o = 8; o < 64; o <<= 1) {
            den += __shfl_xor(den, o);
#pragma unroll
            for (int q = 0; q < 8; ++q) acc[q] += __shfl_xor(acc[q], o);
        }
        float inv = 1.f / (den + 1e-16f);
        if (lane < 8) {
            float r[8];
#pragma unroll
            for (int q = 0; q < 8; ++q) r[q] = acc[q] * inv;
            __half2 p0 = __floats2half2_rn(r[0], r[1]);
            __half2 p1 = __floats2half2_rn(r[2], r[3]);
            __half2 p2 = __floats2half2_rn(r[4], r[5]);
            __half2 p3 = __floats2half2_rn(r[6], r[7]);
            uint4 pk;
            pk.x = *(unsigned*)&p0; pk.y = *(unsigned*)&p1;
            pk.z = *(unsigned*)&p2; pk.w = *(unsigned*)&p3;
            *(uint4*)(z + (size_t)n * 64 + 8 * lane) = pk;
        }
    }
}

// ---------------- K-tiled MFMA GEMM with bias/relu (z-path) ------------------
template <int KK, typename OUTT, bool RELU>
__global__ __launch_bounds__(256) void gemm_kt(const __half* __restrict__ A,
                                               const __half* __restrict__ BT,
                                               const float* __restrict__ bias,
                                               OUTT* __restrict__ C,
                                               int M, int Nout) {
    __shared__ __align__(16) __half As[64 * 72];
    __shared__ __align__(16) __half Bs[64 * 72];
    int tid = threadIdx.x;
    int bm = blockIdx.y * 64, bn = blockIdx.x * 64;
    int wv = tid >> 6, l = tid & 63, lr = l & 15, g = l >> 4;
    float4v acc[4] = {{0.f, 0.f, 0.f, 0.f}, {0.f, 0.f, 0.f, 0.f},
                      {0.f, 0.f, 0.f, 0.f}, {0.f, 0.f, 0.f, 0.f}};
    for (int kc = 0; kc < KK; kc += 64) {
        __syncthreads();
        for (int idx = tid; idx < 512; idx += 256) {
            int row = idx >> 3, ko = (idx & 7) * 8;
            uint4 v = make_uint4(0u, 0u, 0u, 0u);
            int gr = bm + row;
            if (gr < M) v = *(const uint4*)(A + (size_t)gr * KK + kc + ko);
            *(uint4*)(&As[row * 72 + ko]) = v;
            uint4 wvv = *(const uint4*)(BT + (size_t)(bn + row) * KK + kc + ko);
            *(uint4*)(&Bs[row * 72 + ko]) = wvv;
        }
        __syncthreads();
#pragma unroll
        for (int k0 = 0; k0 < 64; k0 += 32) {
            half8v af = *reinterpret_cast<const half8v*>(&As[(16 * wv + lr) * 72 + k0 + 8 * g]);
#pragma unroll
            for (int nt = 0; nt < 4; ++nt) {
                half8v bf = *reinterpret_cast<const half8v*>(&Bs[(nt * 16 + lr) * 72 + k0 + 8 * g]);
                acc[nt] = __builtin_amdgcn_mfma_f32_16x16x32_f16(af, bf, acc[nt], 0, 0, 0);
            }
        }
    }
#pragma unroll
    for (int nt = 0; nt < 4; ++nt) {
        float b = bias[bn + nt * 16 + lr];
#pragma unroll
        for (int r = 0; r < 4; ++r) {
            int grow = bm + 16 * wv + 4 * g + r;
            if (grow < M) {
                float c = acc[nt][r] + b;
                if (RELU) c = fmaxf(c, 0.f);
                if constexpr (sizeof(OUTT) == 2)
                    C[(size_t)grow * Nout + bn + nt * 16 + lr] = __float2half(c);
                else
                    C[(size_t)grow * Nout + bn + nt * 16 + lr] = c;
            }
        }
    }
}

// ------- dec0 gather + fused dec1 scores, persistent waves -------------------
__global__ __launch_bounds__(256) void gat_gather_d08s(const float* __restrict__ hsrc,
                                                       const float* __restrict__ es16,
                                                       const float* __restrict__ ed16,
                                                       const int* __restrict__ off,
                                                       const int* __restrict__ esrc,
                                                       const int* __restrict__ batch,
                                                       const float* __restrict__ bias,
                                                       const float* __restrict__ ws2,
                                                       const float* __restrict__ wd2,
                                                       __half* __restrict__ out,
                                                       float* __restrict__ es2,
                                                       float* __restrict__ ed2, int N) {
    int wid = (blockIdx.x * blockDim.x + threadIdx.x) >> 6;
    int nw = (gridDim.x * blockDim.x) >> 6;
    int lane = threadIdx.x & 63;
    int k8 = lane >> 3, q8 = lane & 7;

    for (int n = wid; n < N; n += nw) {
        int j0 = off[n], j1 = off[n + 1];
        float edv = ed16[batch[n]];
        float acc[8] = {};
        float denacc = 0.f;
        for (int j = j0; j < j1; j += 8) {
            int jj = j + k8;
            int jc = (jj < j1) ? jj : (j1 - 1);
            int g = batch[esrc[jc]];
            float v = es16[g] + edv;
            v = (v > 0.f) ? v : 0.2f * v;
            float pm = (jj < j1) ? expf(v) : 0.f;
            denacc += pm;
            const float* row = hsrc + (size_t)g * 64 + 8 * q8;
            float4 r0 = *(const float4*)row;
            float4 r1 = *(const float4*)(row + 4);
            acc[0] += pm * r0.x; acc[1] += pm * r0.y;
            acc[2] += pm * r0.z; acc[3] += pm * r0.w;
            acc[4] += pm * r1.x; acc[5] += pm * r1.y;
            acc[6] += pm * r1.z; acc[7] += pm * r1.w;
        }

        float den = denacc;
#pragma unroll
        for (int o = 8; o < 64; o <<= 1) {
            den += __shfl_xor(den, o);
#pragma unroll
            for (int q = 0; q < 8; ++q) acc[q] += __shfl_xor(acc[q], o);
        }
        float inv = 1.f / (den + 1e-16f);
        if (lane < 8) {
            int cbase = 8 * lane;
            float r[8];
#pragma unroll
            for (int q = 0; q < 8; ++q) r[q] = fmaxf(acc[q] * inv + bias[cbase + q], 0.f);
            __half2 p0 = __floats2half2_rn(r[0], r[1]);
            __half2 p1 = __floats2half2_rn(r[2], r[3]);
            __half2 p2 = __floats2half2_rn(r[4], r[5]);
            __half2 p3 = __floats2half2_rn(r[6], r[7]);
            uint4 pk;
            pk.x = *(unsigned*)&p0; pk.y = *(unsigned*)&p1;
            pk.z = *(unsigned*)&p2; pk.w = *(unsigned*)&p3;
            *(uint4*)(out + (size_t)n * 64 + cbase) = pk;
            float ps = 0.f, pd = 0.f;
#pragma unroll
            for (int q = 0; q < 8; ++q) {
                ps += r[q] * ws2[cbase + q];
                pd += r[q] * wd2[cbase + q];
            }
#pragma unroll
            for (int o = 1; o < 8; o <<= 1) {
                ps += __shfl_xor(ps, o);
                pd += __shfl_xor(pd, o);
            }
            if (lane == 0) {
                es2[n] = ps;
                ed2[n] = pd;
            }
        }
    }
}

// ---- gate via MFMA + FUSED pooled sum ---------------------------------------
__global__ __launch_bounds__(256) void gate_pool_mfma(const __half* __restrict__ A,
                                                      const __half* __restrict__ BT,
                                                      const float* __restrict__ b1,
                                                      const float* __restrict__ w2,
                                                      const float* __restrict__ b2,
                                                      const int* __restrict__ batch,
                                                      float* __restrict__ pg,
                                                      float* __restrict__ gden,
                                                      float* __restrict__ pooled, int M) {
    constexpr int KP = 72;
    __shared__ __align__(16) __half As[64 * KP];
    __shared__ __align__(16) __half Bs[64 * KP];
    __shared__ float part[16];
    __shared__ float sp[64];
    __shared__ int sb[64];
    int tid = threadIdx.x;
    if (tid < 16) part[tid] = 0.f;
    int bm = blockIdx.x * 64;
    for (int idx = tid; idx < 512; idx += 256) {
        int row = idx >> 3, ko = (idx & 7) * 8;
        uint4 v = make_uint4(0u, 0u, 0u, 0u);
        int gr = bm + row;
        if (gr < M) v = *(const uint4*)(A + (size_t)gr * 64 + ko);
        *(uint4*)(&As[row * KP + ko]) = v;
        uint4 wvv = *(const uint4*)(BT + (size_t)row * 64 + ko);
        *(uint4*)(&Bs[row * KP + ko]) = wvv;
    }
    __syncthreads();
    int wv_ = tid >> 6, l = tid & 63;
    int lr = l & 15, g = l >> 4;
    float4v acc[4] = {{0.f, 0.f, 0.f, 0.f}, {0.f, 0.f, 0.f, 0.f},
                      {0.f, 0.f, 0.f, 0.f}, {0.f, 0.f, 0.f, 0.f}};
    const __half* ap = &As[(16 * wv_ + lr) * KP + 8 * g];
    const __half* bp = &Bs[lr * KP + 8 * g];
#pragma unroll
    for (int k0 = 0; k0 < 64; k0 += 32) {
        half8v af = *reinterpret_cast<const half8v*>(ap + k0);
#pragma unroll
        for (int nt = 0; nt < 4; ++nt) {
            half8v bf = *reinterpret_cast<const half8v*>(bp + nt * 16 * KP + k0);
            acc[nt] = __builtin_amdgcn_mfma_f32_16x16x32_f16(af, bf, acc[nt], 0, 0, 0);
        }
    }
    float partial[4];
#pragma unroll
    for (int r = 0; r < 4; ++r) {
        float t = 0.f;
#pragma unroll
        for (int nt = 0; nt < 4; ++nt) {
            int col = nt * 16 + lr;
            float tv = acc[nt][r] + b1[col];
            tv = fmaxf(tv, 0.f);
            t += tv * w2[col];
        }
        partial[r] = t;
    }
#pragma unroll
    for (int o = 1; o < 16; o <<= 1)
#pragma unroll
        for (int r = 0; r < 4; ++r) partial[r] += __shfl_xor(partial[r], o);
    if (lr == 0) {
        float bb = b2[0];
#pragma unroll
        for (int r = 0; r < 4; ++r) {
            int row = 16 * wv_ + 4 * g + r;
            int grow = bm + row;
            if (grow < M) {
                float p = expf(partial[r] + bb);
                pg[grow] = p;
                int bg = batch[grow];
                sp[row] = p;
                sb[row] = bg;
                atomicAdd(&part[bg], p);
            }
        }
    }
    __syncthreads();
    if (tid < 16 && part[tid] != 0.f) atomicAdd(&gden[tid], part[tid]);
    if (tid < 64) {
        int nrows = min(64, M - bm);
        int curg = sb[0];
        float acc2 = 0.f;
        for (int row = 0; row < nrows; ++row) {
            int g2 = sb[row];
            if (g2 != curg) {
                atomicAdd(&pooled[curg * 64 + tid], acc2);
                acc2 = 0.f;
                curg = g2;
            }
            acc2 += sp[row] * __half2float(As[row * KP + tid]);
        }
        atomicAdd(&pooled[curg * 64 + tid], acc2);
    }
}

__global__ void dec_prep(const float* __restrict__ pooled, const float* __restrict__ gden,
                         const float* __restrict__ Wd0, const float* __restrict__ asd,
                         const float* __restrict__ add, float* __restrict__ hd016,
                         float* __restrict__ es16, float* __restrict__ ed16) {
    int g = blockIdx.x;
    int lane = threadIdx.x;
    float pn = pooled[g * 64 + lane] / (gden[g] + 1e-16f);
    float o = 0.f;
    for (int c = 0; c < 64; ++c) o += __shfl(pn, c) * Wd0[c * 64 + lane];
    hd016[g * 64 + lane] = o;
    float s = o * asd[lane], d = o * add[lane];
#pragma unroll
    for (int off = 32; off; off >>= 1) {
        s += __shfl_xor(s, off);
        d += __shfl_xor(d, off);
    }
    if (lane == 0) {
        es16[g] = s;
        ed16[g] = d;
    }
}

// ---------------- host ----------------
static inline int cdiv(int a, int b) { return (a + b - 1) / b; }
static inline size_t al256(size_t b) { return (b + 255) & ~(size_t)255; }

extern "C" void kernel_launch(void* const* d_in, const int* in_sizes, int n_in,
                              void* d_out, int out_size, void* d_ws, size_t ws_size,
                              hipStream_t stream) {
    const float* x      = (const float*)d_in[0];
    const int*   ei     = (const int*)  d_in[1];
    const int*   batch  = (const int*)  d_in[2];
    const float* W_e0   = (const float*)d_in[3];
    const float* a_s_e0 = (const float*)d_in[4];
    const float* a_d_e0 = (const float*)d_in[5];
    const float* b_e0   = (const float*)d_in[6];
    const float* W_e1   = (const float*)d_in[7];
    const float* a_s_e1 = (const float*)d_in[8];
    const float* a_d_e1 = (const float*)d_in[9];
    const float* b_e1   = (const float*)d_in[10];
    const float* W_d0   = (const float*)d_in[11];
    const float* a_s_d0 = (const float*)d_in[12];
    const float* a_d_d0 = (const float*)d_in[13];
    const float* b_d0   = (const float*)d_in[14];
    const float* W_d1   = (const float*)d_in[15];
    const float* a_s_d1 = (const float*)d_in[16];
    const float* a_d_d1 = (const float*)d_in[17];
    const float* b_d1   = (const float*)d_in[18];
    const float* g_w1   = (const float*)d_in[19];
    const float* g_b1   = (const float*)d_in[20];
    const float* g_w2   = (const float*)d_in[21];
    const float* g_b2   = (const float*)d_in[22];

    const int N    = in_sizes[2];
    const int E    = in_sizes[1] / 2;
    const int Etot = E + N;
    const int Din  = in_sizes[0] / N;  // 128

    char* w = (char*)d_ws;
    size_t o = 0;
    auto alloc = [&](size_t bytes) -> void* {
        void* p = w + o;
        o = al256(o + bytes);
        return p;
    };
    __half*   h16    = (__half*)  alloc((size_t)N * 512 * 2);  // enc0 h / enc1 z / dec1 z
    __half*   bufA   = (__half*)  alloc((size_t)N * 64 * 2);
    __half*   bufB   = (__half*)  alloc((size_t)N * 64 * 2);
    __half*   wt_e0  = (__half*)  alloc((size_t)512 * 128 * 2);
    __half*   wst_e1 = (__half*)  alloc((size_t)64 * 512 * 2);
    __half*   wst_d1 = (__half*)  alloc((size_t)128 * 64 * 2);
    __half*   wt_g1  = (__half*)  alloc((size_t)64 * 64 * 2);
    float*    ws_e0  = (float*)   alloc(8 * 128 * 4);
    float*    wd_e0  = (float*)   alloc(8 * 128 * 4);
    float*    ws_e1  = (float*)   alloc(8 * 64 * 4);
    float*    wd_e1  = (float*)   alloc(8 * 64 * 4);
    float*    ws_d1  = (float*)   alloc(64 * 4);
    float*    wd_d1  = (float*)   alloc(64 * 4);
    float*    es     = (float*)   alloc((size_t)N * 8 * 4);
    float*    ed     = (float*)   alloc((size_t)N * 8 * 4);
    float*    pg     = (float*)   alloc((size_t)N * 4);
    int*      off    = (int*)     alloc((size_t)(N + 1) * 4);
    int*      cnt    = (int*)     alloc((size_t)N * 4);   // cnt+cur adjacent; memset
    int*      cur    = (int*)     alloc((size_t)N * 4);   // uses padded size below
    int*      esrc   = (int*)     alloc((size_t)Etot * 4);
    int*      bsum   = (int*)     alloc(256 * 4);
    float*    gden   = (float*)   alloc(16 * 4);          // gden+pooled adjacent
    float*    pooled = (float*)   alloc(16 * 64 * 4);
    float*    hd016  = (float*)   alloc(16 * 64 * 4);
    float*    es16   = (float*)   alloc(16 * 4);
    float*    ed16   = (float*)   alloc(16 * 4);
    (void)ws_size; (void)n_in; (void)out_size;

    const int persistGrid = 2048;                 // ~8 blocks/CU, waves stay resident
    const int nodeThreadGrid = cdiv(N, TB);
    const int edgeGrid     = cdiv(Etot, TB);
    const int scanBlocks   = cdiv(N, 256);

    // ---- CSR: memset covers cnt's PADDED extent + cur (fixes R17 crash) ----
    hipMemsetAsync(cnt, 0, al256((size_t)N * 4) + (size_t)N * 4, stream);
    csr_count<<<edgeGrid, TB, 0, stream>>>(ei, E, Etot, cnt);
    scan_phase1<<<scanBlocks, 256, 0, stream>>>(cnt, esrc /*temp incl*/, bsum, N);
    scan_phase2<<<1, 256, 0, stream>>>(bsum, scanBlocks);
    scan_phase3<<<scanBlocks, 256, 0, stream>>>(esrc, bsum, off, N);
    csr_fill<<<edgeGrid, TB, 0, stream>>>(ei, E, Etot, off, cur, esrc);

    // ---- merged prep (1 launch) ----
    prep_all<<<cdiv(112192, TB), TB, 0, stream>>>(W_e0, g_w1, W_e1, W_d1,
                                                  a_s_e0, a_d_e0, a_s_e1, a_d_e1,
                                                  a_s_d1, a_d_d1,
                                                  wt_e0, wt_g1, wst_e1, wst_d1,
                                                  ws_e0, wd_e0, ws_e1, wd_e1, ws_d1, wd_d1);

    // ---- encoder layer 0 (H=8, relu): self-casting GEMM, fp32 scores ----
    scores_f32<128, 8><<<nodeThreadGrid, TB, 0, stream>>>(x, ws_e0, wd_e0, es, ed, N);
    {
        dim3 grid(512 / 128, cdiv(N, 64));
        gemm_mfma_wide_f32<<<grid, TB, 0, stream>>>(x, wt_e0, h16, N, 512);
    }
    gat_gather_h8<true><<<persistGrid, TB, 0, stream>>>(
        h16, es, ed, off, esrc, b_e0, bufA, N);

    // ---- encoder layer 1 (H=8, no relu): z-path ----
    scores_nt<64, 8><<<nodeThreadGrid, TB, 0, stream>>>(bufA, ws_e1, wd_e1, es, ed, N);
    gat_gather_zh8<<<persistGrid, TB, 0, stream>>>(bufA, es, ed, off, esrc, h16 /*z*/, N);
    {
        dim3 grid(1, cdiv(N, 64));
        gemm_kt<512, __half, false><<<grid, TB, 0, stream>>>(h16 /*z*/, wst_e1, b_e1, bufB, N, 64);
    }

    // ---- pooling (gate + pooled sum fused) ----
    hipMemsetAsync(gden, 0, al256(16 * 4) + 16 * 64 * 4, stream);
    gate_pool_mfma<<<cdiv(N, 64), TB, 0, stream>>>(bufB, wt_g1, g_b1, g_w2, g_b2,
                                                   batch, pg, gden, pooled, N);
    dec_prep<<<16, 64, 0, stream>>>(pooled, gden, W_d0, a_s_d0, a_d_d0, hd016, es16, ed16);

    // ---- decoder layer 0 (H=1, relu) + fused dec1 scores ----
    gat_gather_d08s<<<persistGrid, TB, 0, stream>>>(
        hd016, es16, ed16, off, esrc, batch, b_d0, ws_d1, wd_d1, bufA, es, ed, N);

    // ---- decoder layer 1 (H=1, C=128, no relu): z-path -> d_out ----
    gat_gather_z8<<<persistGrid, TB, 0, stream>>>(bufA, es, ed, off, esrc, h16 /*z*/, N);
    {
        dim3 grid(2, cdiv(N, 64));
        gemm_kt<64, float, false><<<grid, TB, 0, stream>>>(h16 /*z*/, wst_d1, b_d1, (float*)d_out, N, 128);
    }
}

// Round 19
// 314.115 us; speedup vs baseline: 1.1757x; 1.0274x over previous
//
#include <hip/hip_runtime.h>
#include <hip/hip_fp16.h>
#include <math.h>

#define TB 256

typedef _Float16 half8v __attribute__((ext_vector_type(8)));
typedef float float4v __attribute__((ext_vector_type(4)));

static __device__ __forceinline__ int edge_src(const int* ei, int E, int e) {
    return (e < E) ? ei[e] : (e - E);
}
static __device__ __forceinline__ int edge_dst(const int* ei, int E, int e) {
    return (e < E) ? ei[E + e] : (e - E);
}

// ---------------- CSR build ----------------
__global__ void csr_count(const int* __restrict__ ei, int E, int Etot, int* __restrict__ cnt) {
    int e = blockIdx.x * blockDim.x + threadIdx.x;
    if (e >= Etot) return;
    atomicAdd(&cnt[edge_dst(ei, E, e)], 1);
}

__global__ __launch_bounds__(256) void scan_phase1(const int* __restrict__ cnt,
                                                   int* __restrict__ incl,
                                                   int* __restrict__ bsum, int n) {
    __shared__ int sdata[256];
    int t = threadIdx.x;
    int base = blockIdx.x * 256;
    int v = (base + t < n) ? cnt[base + t] : 0;
    for (int d = 1; d < 256; d <<= 1) {
        sdata[t] = v; __syncthreads();
        if (t >= d) v += sdata[t - d];
        __syncthreads();
    }
    if (base + t < n) incl[base + t] = v;
    if (t == 255) bsum[blockIdx.x] = v;
}

__global__ void scan_phase2(int* bsum, int nb) {
    __shared__ int sdata[256];
    int t = threadIdx.x;
    int v = (t < nb) ? bsum[t] : 0;
    for (int d = 1; d < 256; d <<= 1) {
        sdata[t] = v; __syncthreads();
        if (t >= d) v += sdata[t - d];
        __syncthreads();
    }
    if (t < nb) bsum[t] = v;
}

__global__ __launch_bounds__(256) void scan_phase3(const int* __restrict__ incl,
                                                   const int* __restrict__ bsum,
                                                   int* __restrict__ off, int n) {
    int i = blockIdx.x * 256 + threadIdx.x;
    if (i < n) off[i + 1] = incl[i] + (blockIdx.x ? bsum[blockIdx.x - 1] : 0);
    if (i == 0) off[0] = 0;
}

__global__ void csr_fill(const int* __restrict__ ei, int E, int Etot,
                         const int* __restrict__ off, int* __restrict__ cur,
                         int* __restrict__ esrc) {
    int e = blockIdx.x * blockDim.x + threadIdx.x;
    if (e >= Etot) return;
    int d = edge_dst(ei, E, e);
    int pos = atomicAdd(&cur[d], 1);
    esrc[off[d] + pos] = edge_src(ei, E, e);
}

// ------ merged weight prep (all transposes/stacks + folded ws in ONE launch) -
__global__ void prep_all(const float* __restrict__ W_e0, const float* __restrict__ g_w1,
                         const float* __restrict__ W_e1, const float* __restrict__ W_d1,
                         const float* __restrict__ a_s_e0, const float* __restrict__ a_d_e0,
                         const float* __restrict__ a_s_e1, const float* __restrict__ a_d_e1,
                         const float* __restrict__ a_s_d1, const float* __restrict__ a_d_d1,
                         __half* __restrict__ wt_e0, __half* __restrict__ wt_g1,
                         __half* __restrict__ wst_e1, __half* __restrict__ wst_d1,
                         float* __restrict__ ws_e0, float* __restrict__ wd_e0,
                         float* __restrict__ ws_e1, float* __restrict__ wd_e1,
                         float* __restrict__ ws_d1, float* __restrict__ wd_d1) {
    int i = blockIdx.x * blockDim.x + threadIdx.x;
    if (i < 65536) {
        int nn = i / 128, kk = i % 128;
        wt_e0[i] = __float2half(W_e0[kk * 512 + nn]);
    } else if (i < 69632) {
        int j = i - 65536;
        int nn = j / 64, kk = j % 64;
        wt_g1[j] = __float2half(g_w1[kk * 64 + nn]);
    } else if (i < 102400) {
        int j = i - 69632;
        int c = j / 512, rem = j % 512;
        int h = rem / 64, k = rem % 64;
        wst_e1[j] = __float2half(W_e1[(size_t)k * 512 + h * 64 + c]);
    } else if (i < 110592) {
        int j = i - 102400;
        int c = j / 64, k = j % 64;
        wst_d1[j] = __float2half(W_d1[(size_t)k * 128 + c]);
    } else if (i < 112192) {
        int jj = i - 110592;
        const float* W; const float* as_; const float* ad_;
        float* ws; float* wd;
        int K, H, C, j;
        if (jj < 1024) { j = jj; K = 128; H = 8; C = 64; W = W_e0; as_ = a_s_e0; ad_ = a_d_e0; ws = ws_e0; wd = wd_e0; }
        else if (jj < 1536) { j = jj - 1024; K = 64; H = 8; C = 64; W = W_e1; as_ = a_s_e1; ad_ = a_d_e1; ws = ws_e1; wd = wd_e1; }
        else { j = jj - 1536; K = 64; H = 1; C = 128; W = W_d1; as_ = a_s_d1; ad_ = a_d_d1; ws = ws_d1; wd = wd_d1; }
        int h = j / K, k = j % K;
        const float* wrow = W + (size_t)k * H * C + h * C;
        float s = 0.f, d = 0.f;
        for (int c = 0; c < C; ++c) {
            s += wrow[c] * as_[h * C + c];
            d += wrow[c] * ad_[h * C + c];
        }
        ws[j] = s;
        wd[j] = d;
    }
}

// --- wide MFMA GEMM for enc0, SELF-CASTING fp32 A: BM=64, BN=128, K=128 -----
__global__ __launch_bounds__(256) void gemm_mfma_wide_f32(const float* __restrict__ A,
                                                          const __half* __restrict__ BT,
                                                          __half* __restrict__ C,
                                                          int M, int N) {
    constexpr int K = 128, KP = 136;
    __shared__ __align__(16) __half As[64 * KP];
    __shared__ __align__(16) __half Bs[128 * KP];
    int tid = threadIdx.x;
    int bm = blockIdx.y * 64, bn = blockIdx.x * 128;
    for (int idx = tid; idx < 64 * 16; idx += 256) {
        int row = idx >> 4, ko = (idx & 15) * 8;
        int gr = bm + row;
        uint4 pk = make_uint4(0u, 0u, 0u, 0u);
        if (gr < M) {
            float4 a0 = *(const float4*)(A + (size_t)gr * K + ko);
            float4 a1 = *(const float4*)(A + (size_t)gr * K + ko + 4);
            __half2 h0 = __floats2half2_rn(a0.x, a0.y);
            __half2 h1 = __floats2half2_rn(a0.z, a0.w);
            __half2 h2 = __floats2half2_rn(a1.x, a1.y);
            __half2 h3 = __floats2half2_rn(a1.z, a1.w);
            pk.x = *(unsigned*)&h0; pk.y = *(unsigned*)&h1;
            pk.z = *(unsigned*)&h2; pk.w = *(unsigned*)&h3;
        }
        *(uint4*)(&As[row * KP + ko]) = pk;
    }
    for (int idx = tid; idx < 128 * 16; idx += 256) {
        int row = idx >> 4, ko = (idx & 15) * 8;
        *(uint4*)(&Bs[row * KP + ko]) = *(const uint4*)(BT + (size_t)(bn + row) * K + ko);
    }
    __syncthreads();
    int wv_ = tid >> 6, l = tid & 63;
    int lr = l & 15, g = l >> 4;
    float4v acc[8] = {{0,0,0,0},{0,0,0,0},{0,0,0,0},{0,0,0,0},
                      {0,0,0,0},{0,0,0,0},{0,0,0,0},{0,0,0,0}};
    const __half* ap = &As[(16 * wv_ + lr) * KP + 8 * g];
    const __half* bp = &Bs[lr * KP + 8 * g];
#pragma unroll
    for (int k0 = 0; k0 < K; k0 += 32) {
        half8v af = *reinterpret_cast<const half8v*>(ap + k0);
#pragma unroll
        for (int nt = 0; nt < 8; ++nt) {
            half8v bf = *reinterpret_cast<const half8v*>(bp + nt * 16 * KP + k0);
            acc[nt] = __builtin_amdgcn_mfma_f32_16x16x32_f16(af, bf, acc[nt], 0, 0, 0);
        }
    }
#pragma unroll
    for (int nt = 0; nt < 8; ++nt) {
#pragma unroll
        for (int r = 0; r < 4; ++r) {
            int grow = bm + 16 * wv_ + 4 * g + r;
            if (grow < M)
                C[(size_t)grow * N + bn + nt * 16 + lr] = __float2half(acc[nt][r]);
        }
    }
}

// ------- enc0 scores from fp32 x, thread-per-node --------
template <int K, int H>
__global__ __launch_bounds__(256) void scores_f32(const float* __restrict__ X,
                                                  const float* __restrict__ ws,
                                                  const float* __restrict__ wd,
                                                  float* __restrict__ es,
                                                  float* __restrict__ ed, int N) {
    int n = blockIdx.x * blockDim.x + threadIdx.x;
    if (n >= N) return;
    const float* row = X + (size_t)n * K;
    float s[H] = {}, d[H] = {};
#pragma unroll
    for (int k0 = 0; k0 < K; k0 += 8) {
        float4 a0 = *(const float4*)(row + k0);
        float4 a1 = *(const float4*)(row + k0 + 4);
        float a[8] = {a0.x, a0.y, a0.z, a0.w, a1.x, a1.y, a1.z, a1.w};
#pragma unroll
        for (int h = 0; h < H; ++h)
#pragma unroll
            for (int q = 0; q < 8; ++q) {
                s[h] += a[q] * ws[h * K + k0 + q];
                d[h] += a[q] * wd[h * K + k0 + q];
            }
    }
#pragma unroll
    for (int h = 0; h < H; ++h) {
        es[(size_t)n * H + h] = s[h];
        ed[(size_t)n * H + h] = d[h];
    }
}

// ------- scores, thread-per-node (fp16 input) ------
template <int K, int H>
__global__ __launch_bounds__(256) void scores_nt(const __half* __restrict__ A,
                                                 const float* __restrict__ ws,
                                                 const float* __restrict__ wd,
                                                 float* __restrict__ es,
                                                 float* __restrict__ ed, int N) {
    int n = blockIdx.x * blockDim.x + threadIdx.x;
    if (n >= N) return;
    const __half* row = A + (size_t)n * K;
    float s[H] = {}, d[H] = {};
#pragma unroll
    for (int k0 = 0; k0 < K; k0 += 8) {
        uint4 raw = *(const uint4*)(row + k0);
        const __half* hv = (const __half*)&raw;
        float a[8];
#pragma unroll
        for (int q = 0; q < 8; ++q) a[q] = __half2float(hv[q]);
#pragma unroll
        for (int h = 0; h < H; ++h)
#pragma unroll
            for (int q = 0; q < 8; ++q) {
                s[h] += a[q] * ws[h * K + k0 + q];
                d[h] += a[q] * wd[h * K + k0 + q];
            }
    }
#pragma unroll
    for (int h = 0; h < H; ++h) {
        es[(size_t)n * H + h] = s[h];
        ed[(size_t)n * H + h] = d[h];
    }
}

// ------- enc0 gather, 8-edge chunked, one-shot grid (measured-best 54.4us) ---
template <bool RELU>
__global__ __launch_bounds__(256) void gat_gather_h8(const __half* __restrict__ hsrc,
                                                     const float* __restrict__ es,
                                                     const float* __restrict__ ed,
                                                     const int* __restrict__ off,
                                                     const int* __restrict__ esrc,
                                                     const float* __restrict__ bias,
                                                     __half* __restrict__ out, int N) {
    constexpr int HC = 512;
    int n = (blockIdx.x * blockDim.x + threadIdx.x) >> 6;
    int lane = threadIdx.x & 63;
    if (n >= N) return;
    int hd = lane >> 3;
    int k8 = lane >> 3, h8 = lane & 7;
    int j0 = off[n], j1 = off[n + 1];

    float edl = ed[(size_t)n * 8 + h8];

    float acc[8] = {};
    float denacc = 0.f;
    for (int j = j0; j < j1; j += 8) {
        int jj = j + k8;
        int jc = (jj < j1) ? jj : (j1 - 1);
        int sidx = esrc[jc];
        float v = es[(size_t)sidx * 8 + h8] + edl;
        v = (v > 0.f) ? v : 0.2f * v;
        float pm = (jj < j1) ? expf(v) : 0.f;
        denacc += pm;
        uint4 rw[8];
#pragma unroll
        for (int k = 0; k < 8; ++k) {
            int sb = __shfl(sidx, k * 8);
            rw[k] = *(const uint4*)(hsrc + (size_t)sb * HC + 8 * lane);
        }
#pragma unroll
        for (int k = 0; k < 8; ++k) {
            float a = __shfl(pm, k * 8 + hd);
            const __half* hv = (const __half*)&rw[k];
#pragma unroll
            for (int q = 0; q < 8; ++q) acc[q] += a * __half2float(hv[q]);
        }
    }

    float den = denacc;
#pragma unroll
    for (int o = 8; o < 64; o <<= 1) den += __shfl_xor(den, o);
    float dv = __shfl(den, hd) + 1e-16f;

#pragma unroll
    for (int q = 0; q < 8; ++q) acc[q] /= dv;
#pragma unroll
    for (int o = 8; o < 64; o <<= 1)
#pragma unroll
        for (int q = 0; q < 8; ++q) acc[q] += __shfl_xor(acc[q], o);

    if (lane < 8) {
        int cbase = 8 * lane;
        float r[8];
#pragma unroll
        for (int q = 0; q < 8; ++q) {
            float o2 = acc[q] * 0.125f + bias[cbase + q];
            if (RELU) o2 = fmaxf(o2, 0.f);
            r[q] = o2;
        }
        __half2 p0 = __floats2half2_rn(r[0], r[1]);
        __half2 p1 = __floats2half2_rn(r[2], r[3]);
        __half2 p2 = __floats2half2_rn(r[4], r[5]);
        __half2 p3 = __floats2half2_rn(r[6], r[7]);
        uint4 pk;
        pk.x = *(unsigned*)&p0; pk.y = *(unsigned*)&p1;
        pk.z = *(unsigned*)&p2; pk.w = *(unsigned*)&p3;
        *(uint4*)(out + (size_t)n * 64 + cbase) = pk;
    }
}

// ------- enc1 z-gather, one-shot grid ----------------------------------------
__global__ __launch_bounds__(256) void gat_gather_zh8(const __half* __restrict__ A,
                                                      const float* __restrict__ es,
                                                      const float* __restrict__ ed,
                                                      const int* __restrict__ off,
                                                      const int* __restrict__ esrc,
                                                      __half* __restrict__ z, int N) {
    int n = (blockIdx.x * blockDim.x + threadIdx.x) >> 6;
    int lane = threadIdx.x & 63;
    if (n >= N) return;
    int h = lane >> 3, q = lane & 7;
    int j0 = off[n], j1 = off[n + 1];
    float edv = ed[(size_t)n * 8 + h];

    float acc[8] = {};
    float den = 0.f;
    int j = j0;
    for (; j + 1 < j1; j += 2) {
        int s0 = esrc[j], s1 = esrc[j + 1];
        float v0 = es[(size_t)s0 * 8 + h] + edv;
        float v1 = es[(size_t)s1 * 8 + h] + edv;
        v0 = (v0 > 0.f) ? v0 : 0.2f * v0;
        v1 = (v1 > 0.f) ? v1 : 0.2f * v1;
        float p0 = expf(v0), p1 = expf(v1);
        den += p0 + p1;
        uint4 r0 = *(const uint4*)(A + (size_t)s0 * 64 + 8 * q);
        uint4 r1 = *(const uint4*)(A + (size_t)s1 * 64 + 8 * q);
        const __half* h0 = (const __half*)&r0;
        const __half* h1 = (const __half*)&r1;
#pragma unroll
        for (int k = 0; k < 8; ++k)
            acc[k] += p0 * __half2float(h0[k]) + p1 * __half2float(h1[k]);
    }
    if (j < j1) {
        int s0 = esrc[j];
        float v0 = es[(size_t)s0 * 8 + h] + edv;
        v0 = (v0 > 0.f) ? v0 : 0.2f * v0;
        float p0 = expf(v0);
        den += p0;
        uint4 r0 = *(const uint4*)(A + (size_t)s0 * 64 + 8 * q);
        const __half* h0 = (const __half*)&r0;
#pragma unroll
        for (int k = 0; k < 8; ++k) acc[k] += p0 * __half2float(h0[k]);
    }

    float inv = 1.f / ((den + 1e-16f) * 8.f);
    float r[8];
#pragma unroll
    for (int k = 0; k < 8; ++k) r[k] = acc[k] * inv;
    __half2 p0 = __floats2half2_rn(r[0], r[1]);
    __half2 p1 = __floats2half2_rn(r[2], r[3]);
    __half2 p2 = __floats2half2_rn(r[4], r[5]);
    __half2 p3 = __floats2half2_rn(r[6], r[7]);
    uint4 pk;
    pk.x = *(unsigned*)&p0; pk.y = *(unsigned*)&p1;
    pk.z = *(unsigned*)&p2; pk.w = *(unsigned*)&p3;
    *(uint4*)(z + (size_t)n * 512 + h * 64 + 8 * q) = pk;
}

// -------- dec1 z-gather, one-shot grid ---------------------------------------
__global__ __launch_bounds__(256) void gat_gather_z8(const __half* __restrict__ A,
                                                     const float* __restrict__ es,
                                                     const float* __restrict__ ed,
                                                     const int* __restrict__ off,
                                                     const int* __restrict__ esrc,
                                                     __half* __restrict__ z, int N) {
    int n = (blockIdx.x * blockDim.x + threadIdx.x) >> 6;
    int lane = threadIdx.x & 63;
    if (n >= N) return;
    int k8 = lane >> 3, q8 = lane & 7;
    int j0 = off[n], j1 = off[n + 1];
    float edv = ed[n];

    float acc[8] = {};
    float denacc = 0.f;
    for (int j = j0; j < j1; j += 8) {
        int jj = j + k8;
        int jc = (jj < j1) ? jj : (j1 - 1);
        int sidx = esrc[jc];
        float v = es[sidx] + edv;
        v = (v > 0.f) ? v : 0.2f * v;
        float pm = (jj < j1) ? expf(v) : 0.f;
        denacc += pm;
        uint4 rw = *(const uint4*)(A + (size_t)sidx * 64 + 8 * q8);
        const __half* hv = (const __half*)&rw;
#pragma unroll
        for (int q = 0; q < 8; ++q) acc[q] += pm * __half2float(hv[q]);
    }

    float den = denacc;
#pragma unroll
    for (int o = 8; o < 64; o <<= 1) {
        den += __shfl_xor(den, o);
#pragma unroll
        for (int q = 0; q < 8; ++q) acc[q] += __shfl_xor(acc[q], o);
    }
    float inv = 1.f / (den + 1e-16f);
    if (lane < 8) {
        float r[8];
#pragma unroll
        for (int q = 0; q < 8; ++q) r[q] = acc[q] * inv;
        __half2 p0 = __floats2half2_rn(r[0], r[1]);
        __half2 p1 = __floats2half2_rn(r[2], r[3]);
        __half2 p2 = __floats2half2_rn(r[4], r[5]);
        __half2 p3 = __floats2half2_rn(r[6], r[7]);
        uint4 pk;
        pk.x = *(unsigned*)&p0; pk.y = *(unsigned*)&p1;
        pk.z = *(unsigned*)&p2; pk.w = *(unsigned*)&p3;
        *(uint4*)(z + (size_t)n * 64 + 8 * lane) = pk;
    }
}

// ---------------- K-tiled MFMA GEMM with bias/relu (z-path) ------------------
template <int KK, typename OUTT, bool RELU>
__global__ __launch_bounds__(256) void gemm_kt(const __half* __restrict__ A,
                                               const __half* __restrict__ BT,
                                               const float* __restrict__ bias,
                                               OUTT* __restrict__ C,
                                               int M, int Nout) {
    __shared__ __align__(16) __half As[64 * 72];
    __shared__ __align__(16) __half Bs[64 * 72];
    int tid = threadIdx.x;
    int bm = blockIdx.y * 64, bn = blockIdx.x * 64;
    int wv = tid >> 6, l = tid & 63, lr = l & 15, g = l >> 4;
    float4v acc[4] = {{0.f, 0.f, 0.f, 0.f}, {0.f, 0.f, 0.f, 0.f},
                      {0.f, 0.f, 0.f, 0.f}, {0.f, 0.f, 0.f, 0.f}};
    for (int kc = 0; kc < KK; kc += 64) {
        __syncthreads();
        for (int idx = tid; idx < 512; idx += 256) {
            int row = idx >> 3, ko = (idx & 7) * 8;
            uint4 v = make_uint4(0u, 0u, 0u, 0u);
            int gr = bm + row;
            if (gr < M) v = *(const uint4*)(A + (size_t)gr * KK + kc + ko);
            *(uint4*)(&As[row * 72 + ko]) = v;
            uint4 wvv = *(const uint4*)(BT + (size_t)(bn + row) * KK + kc + ko);
            *(uint4*)(&Bs[row * 72 + ko]) = wvv;
        }
        __syncthreads();
#pragma unroll
        for (int k0 = 0; k0 < 64; k0 += 32) {
            half8v af = *reinterpret_cast<const half8v*>(&As[(16 * wv + lr) * 72 + k0 + 8 * g]);
#pragma unroll
            for (int nt = 0; nt < 4; ++nt) {
                half8v bf = *reinterpret_cast<const half8v*>(&Bs[(nt * 16 + lr) * 72 + k0 + 8 * g]);
                acc[nt] = __builtin_amdgcn_mfma_f32_16x16x32_f16(af, bf, acc[nt], 0, 0, 0);
            }
        }
    }
#pragma unroll
    for (int nt = 0; nt < 4; ++nt) {
        float b = bias[bn + nt * 16 + lr];
#pragma unroll
        for (int r = 0; r < 4; ++r) {
            int grow = bm + 16 * wv + 4 * g + r;
            if (grow < M) {
                float c = acc[nt][r] + b;
                if (RELU) c = fmaxf(c, 0.f);
                if constexpr (sizeof(OUTT) == 2)
                    C[(size_t)grow * Nout + bn + nt * 16 + lr] = __float2half(c);
                else
                    C[(size_t)grow * Nout + bn + nt * 16 + lr] = c;
            }
        }
    }
}

// ------- dec0 gather + fused dec1 scores, one-shot grid ----------------------
__global__ __launch_bounds__(256) void gat_gather_d08s(const float* __restrict__ hsrc,
                                                       const float* __restrict__ es16,
                                                       const float* __restrict__ ed16,
                                                       const int* __restrict__ off,
                                                       const int* __restrict__ esrc,
                                                       const int* __restrict__ batch,
                                                       const float* __restrict__ bias,
                                                       const float* __restrict__ ws2,
                                                       const float* __restrict__ wd2,
                                                       __half* __restrict__ out,
                                                       float* __restrict__ es2,
                                                       float* __restrict__ ed2, int N) {
    int n = (blockIdx.x * blockDim.x + threadIdx.x) >> 6;
    int lane = threadIdx.x & 63;
    if (n >= N) return;
    int k8 = lane >> 3, q8 = lane & 7;
    int j0 = off[n], j1 = off[n + 1];
    float edv = ed16[batch[n]];

    float acc[8] = {};
    float denacc = 0.f;
    for (int j = j0; j < j1; j += 8) {
        int jj = j + k8;
        int jc = (jj < j1) ? jj : (j1 - 1);
        int g = batch[esrc[jc]];
        float v = es16[g] + edv;
        v = (v > 0.f) ? v : 0.2f * v;
        float pm = (jj < j1) ? expf(v) : 0.f;
        denacc += pm;
        const float* row = hsrc + (size_t)g * 64 + 8 * q8;
        float4 r0 = *(const float4*)row;
        float4 r1 = *(const float4*)(row + 4);
        acc[0] += pm * r0.x; acc[1] += pm * r0.y;
        acc[2] += pm * r0.z; acc[3] += pm * r0.w;
        acc[4] += pm * r1.x; acc[5] += pm * r1.y;
        acc[6] += pm * r1.z; acc[7] += pm * r1.w;
    }

    float den = denacc;
#pragma unroll
    for (int o = 8; o < 64; o <<= 1) {
        den += __shfl_xor(den, o);
#pragma unroll
        for (int q = 0; q < 8; ++q) acc[q] += __shfl_xor(acc[q], o);
    }
    float inv = 1.f / (den + 1e-16f);
    if (lane < 8) {
        int cbase = 8 * lane;
        float r[8];
#pragma unroll
        for (int q = 0; q < 8; ++q) r[q] = fmaxf(acc[q] * inv + bias[cbase + q], 0.f);
        __half2 p0 = __floats2half2_rn(r[0], r[1]);
        __half2 p1 = __floats2half2_rn(r[2], r[3]);
        __half2 p2 = __floats2half2_rn(r[4], r[5]);
        __half2 p3 = __floats2half2_rn(r[6], r[7]);
        uint4 pk;
        pk.x = *(unsigned*)&p0; pk.y = *(unsigned*)&p1;
        pk.z = *(unsigned*)&p2; pk.w = *(unsigned*)&p3;
        *(uint4*)(out + (size_t)n * 64 + cbase) = pk;
        float ps = 0.f, pd = 0.f;
#pragma unroll
        for (int q = 0; q < 8; ++q) {
            ps += r[q] * ws2[cbase + q];
            pd += r[q] * wd2[cbase + q];
        }
#pragma unroll
        for (int o = 1; o < 8; o <<= 1) {
            ps += __shfl_xor(ps, o);
            pd += __shfl_xor(pd, o);
        }
        if (lane == 0) {
            es2[n] = ps;
            ed2[n] = pd;
        }
    }
}

// ---- gate via MFMA + FUSED pooled sum ---------------------------------------
__global__ __launch_bounds__(256) void gate_pool_mfma(const __half* __restrict__ A,
                                                      const __half* __restrict__ BT,
                                                      const float* __restrict__ b1,
                                                      const float* __restrict__ w2,
                                                      const float* __restrict__ b2,
                                                      const int* __restrict__ batch,
                                                      float* __restrict__ pg,
                                                      float* __restrict__ gden,
                                                      float* __restrict__ pooled, int M) {
    constexpr int KP = 72;
    __shared__ __align__(16) __half As[64 * KP];
    __shared__ __align__(16) __half Bs[64 * KP];
    __shared__ float part[16];
    __shared__ float sp[64];
    __shared__ int sb[64];
    int tid = threadIdx.x;
    if (tid < 16) part[tid] = 0.f;
    int bm = blockIdx.x * 64;
    for (int idx = tid; idx < 512; idx += 256) {
        int row = idx >> 3, ko = (idx & 7) * 8;
        uint4 v = make_uint4(0u, 0u, 0u, 0u);
        int gr = bm + row;
        if (gr < M) v = *(const uint4*)(A + (size_t)gr * 64 + ko);
        *(uint4*)(&As[row * KP + ko]) = v;
        uint4 wvv = *(const uint4*)(BT + (size_t)row * 64 + ko);
        *(uint4*)(&Bs[row * KP + ko]) = wvv;
    }
    __syncthreads();
    int wv_ = tid >> 6, l = tid & 63;
    int lr = l & 15, g = l >> 4;
    float4v acc[4] = {{0.f, 0.f, 0.f, 0.f}, {0.f, 0.f, 0.f, 0.f},
                      {0.f, 0.f, 0.f, 0.f}, {0.f, 0.f, 0.f, 0.f}};
    const __half* ap = &As[(16 * wv_ + lr) * KP + 8 * g];
    const __half* bp = &Bs[lr * KP + 8 * g];
#pragma unroll
    for (int k0 = 0; k0 < 64; k0 += 32) {
        half8v af = *reinterpret_cast<const half8v*>(ap + k0);
#pragma unroll
        for (int nt = 0; nt < 4; ++nt) {
            half8v bf = *reinterpret_cast<const half8v*>(bp + nt * 16 * KP + k0);
            acc[nt] = __builtin_amdgcn_mfma_f32_16x16x32_f16(af, bf, acc[nt], 0, 0, 0);
        }
    }
    float partial[4];
#pragma unroll
    for (int r = 0; r < 4; ++r) {
        float t = 0.f;
#pragma unroll
        for (int nt = 0; nt < 4; ++nt) {
            int col = nt * 16 + lr;
            float tv = acc[nt][r] + b1[col];
            tv = fmaxf(tv, 0.f);
            t += tv * w2[col];
        }
        partial[r] = t;
    }
#pragma unroll
    for (int o = 1; o < 16; o <<= 1)
#pragma unroll
        for (int r = 0; r < 4; ++r) partial[r] += __shfl_xor(partial[r], o);
    if (lr == 0) {
        float bb = b2[0];
#pragma unroll
        for (int r = 0; r < 4; ++r) {
            int row = 16 * wv_ + 4 * g + r;
            int grow = bm + row;
            if (grow < M) {
                float p = expf(partial[r] + bb);
                pg[grow] = p;
                int bg = batch[grow];
                sp[row] = p;
                sb[row] = bg;
                atomicAdd(&part[bg], p);
            }
        }
    }
    __syncthreads();
    if (tid < 16 && part[tid] != 0.f) atomicAdd(&gden[tid], part[tid]);
    if (tid < 64) {
        int nrows = min(64, M - bm);
        int curg = sb[0];
        float acc2 = 0.f;
        for (int row = 0; row < nrows; ++row) {
            int g2 = sb[row];
            if (g2 != curg) {
                atomicAdd(&pooled[curg * 64 + tid], acc2);
                acc2 = 0.f;
                curg = g2;
            }
            acc2 += sp[row] * __half2float(As[row * KP + tid]);
        }
        atomicAdd(&pooled[curg * 64 + tid], acc2);
    }
}

__global__ void dec_prep(const float* __restrict__ pooled, const float* __restrict__ gden,
                         const float* __restrict__ Wd0, const float* __restrict__ asd,
                         const float* __restrict__ add, float* __restrict__ hd016,
                         float* __restrict__ es16, float* __restrict__ ed16) {
    int g = blockIdx.x;
    int lane = threadIdx.x;
    float pn = pooled[g * 64 + lane] / (gden[g] + 1e-16f);
    float o = 0.f;
    for (int c = 0; c < 64; ++c) o += __shfl(pn, c) * Wd0[c * 64 + lane];
    hd016[g * 64 + lane] = o;
    float s = o * asd[lane], d = o * add[lane];
#pragma unroll
    for (int off = 32; off; off >>= 1) {
        s += __shfl_xor(s, off);
        d += __shfl_xor(d, off);
    }
    if (lane == 0) {
        es16[g] = s;
        ed16[g] = d;
    }
}

// ---------------- host ----------------
static inline int cdiv(int a, int b) { return (a + b - 1) / b; }
static inline size_t al256(size_t b) { return (b + 255) & ~(size_t)255; }

extern "C" void kernel_launch(void* const* d_in, const int* in_sizes, int n_in,
                              void* d_out, int out_size, void* d_ws, size_t ws_size,
                              hipStream_t stream) {
    const float* x      = (const float*)d_in[0];
    const int*   ei     = (const int*)  d_in[1];
    const int*   batch  = (const int*)  d_in[2];
    const float* W_e0   = (const float*)d_in[3];
    const float* a_s_e0 = (const float*)d_in[4];
    const float* a_d_e0 = (const float*)d_in[5];
    const float* b_e0   = (const float*)d_in[6];
    const float* W_e1   = (const float*)d_in[7];
    const float* a_s_e1 = (const float*)d_in[8];
    const float* a_d_e1 = (const float*)d_in[9];
    const float* b_e1   = (const float*)d_in[10];
    const float* W_d0   = (const float*)d_in[11];
    const float* a_s_d0 = (const float*)d_in[12];
    const float* a_d_d0 = (const float*)d_in[13];
    const float* b_d0   = (const float*)d_in[14];
    const float* W_d1   = (const float*)d_in[15];
    const float* a_s_d1 = (const float*)d_in[16];
    const float* a_d_d1 = (const float*)d_in[17];
    const float* b_d1   = (const float*)d_in[18];
    const float* g_w1   = (const float*)d_in[19];
    const float* g_b1   = (const float*)d_in[20];
    const float* g_w2   = (const float*)d_in[21];
    const float* g_b2   = (const float*)d_in[22];

    const int N    = in_sizes[2];
    const int E    = in_sizes[1] / 2;
    const int Etot = E + N;
    const int Din  = in_sizes[0] / N;  // 128

    char* w = (char*)d_ws;
    size_t o = 0;
    auto alloc = [&](size_t bytes) -> void* {
        void* p = w + o;
        o = al256(o + bytes);
        return p;
    };
    __half*   h16    = (__half*)  alloc((size_t)N * 512 * 2);  // enc0 h / enc1 z / dec1 z
    __half*   bufA   = (__half*)  alloc((size_t)N * 64 * 2);
    __half*   bufB   = (__half*)  alloc((size_t)N * 64 * 2);
    __half*   wt_e0  = (__half*)  alloc((size_t)512 * 128 * 2);
    __half*   wst_e1 = (__half*)  alloc((size_t)64 * 512 * 2);
    __half*   wst_d1 = (__half*)  alloc((size_t)128 * 64 * 2);
    __half*   wt_g1  = (__half*)  alloc((size_t)64 * 64 * 2);
    float*    ws_e0  = (float*)   alloc(8 * 128 * 4);
    float*    wd_e0  = (float*)   alloc(8 * 128 * 4);
    float*    ws_e1  = (float*)   alloc(8 * 64 * 4);
    float*    wd_e1  = (float*)   alloc(8 * 64 * 4);
    float*    ws_d1  = (float*)   alloc(64 * 4);
    float*    wd_d1  = (float*)   alloc(64 * 4);
    float*    es     = (float*)   alloc((size_t)N * 8 * 4);
    float*    ed     = (float*)   alloc((size_t)N * 8 * 4);
    float*    pg     = (float*)   alloc((size_t)N * 4);
    int*      off    = (int*)     alloc((size_t)(N + 1) * 4);
    int*      cnt    = (int*)     alloc((size_t)N * 4);   // cnt+cur adjacent; memset
    int*      cur    = (int*)     alloc((size_t)N * 4);   // uses padded size below
    int*      esrc   = (int*)     alloc((size_t)Etot * 4);
    int*      bsum   = (int*)     alloc(256 * 4);
    float*    gden   = (float*)   alloc(16 * 4);          // gden+pooled adjacent
    float*    pooled = (float*)   alloc(16 * 64 * 4);
    float*    hd016  = (float*)   alloc(16 * 64 * 4);
    float*    es16   = (float*)   alloc(16 * 4);
    float*    ed16   = (float*)   alloc(16 * 4);
    (void)ws_size; (void)n_in; (void)out_size;

    const int nodeWaveGrid = cdiv(N, 4);
    const int nodeThreadGrid = cdiv(N, TB);
    const int edgeGrid     = cdiv(Etot, TB);
    const int scanBlocks   = cdiv(N, 256);

    // ---- CSR: memset covers cnt's padded extent + cur ----
    hipMemsetAsync(cnt, 0, al256((size_t)N * 4) + (size_t)N * 4, stream);
    csr_count<<<edgeGrid, TB, 0, stream>>>(ei, E, Etot, cnt);
    scan_phase1<<<scanBlocks, 256, 0, stream>>>(cnt, esrc /*temp incl*/, bsum, N);
    scan_phase2<<<1, 256, 0, stream>>>(bsum, scanBlocks);
    scan_phase3<<<scanBlocks, 256, 0, stream>>>(esrc, bsum, off, N);
    csr_fill<<<edgeGrid, TB, 0, stream>>>(ei, E, Etot, off, cur, esrc);

    // ---- merged prep (1 launch) ----
    prep_all<<<cdiv(112192, TB), TB, 0, stream>>>(W_e0, g_w1, W_e1, W_d1,
                                                  a_s_e0, a_d_e0, a_s_e1, a_d_e1,
                                                  a_s_d1, a_d_d1,
                                                  wt_e0, wt_g1, wst_e1, wst_d1,
                                                  ws_e0, wd_e0, ws_e1, wd_e1, ws_d1, wd_d1);

    // ---- encoder layer 0 (H=8, relu): self-casting GEMM, fp32 scores ----
    scores_f32<128, 8><<<nodeThreadGrid, TB, 0, stream>>>(x, ws_e0, wd_e0, es, ed, N);
    {
        dim3 grid(512 / 128, cdiv(N, 64));
        gemm_mfma_wide_f32<<<grid, TB, 0, stream>>>(x, wt_e0, h16, N, 512);
    }
    gat_gather_h8<true><<<nodeWaveGrid, TB, 0, stream>>>(
        h16, es, ed, off, esrc, b_e0, bufA, N);

    // ---- encoder layer 1 (H=8, no relu): z-path ----
    scores_nt<64, 8><<<nodeThreadGrid, TB, 0, stream>>>(bufA, ws_e1, wd_e1, es, ed, N);
    gat_gather_zh8<<<nodeWaveGrid, TB, 0, stream>>>(bufA, es, ed, off, esrc, h16 /*z*/, N);
    {
        dim3 grid(1, cdiv(N, 64));
        gemm_kt<512, __half, false><<<grid, TB, 0, stream>>>(h16 /*z*/, wst_e1, b_e1, bufB, N, 64);
    }

    // ---- pooling (gate + pooled sum fused) ----
    hipMemsetAsync(gden, 0, al256(16 * 4) + 16 * 64 * 4, stream);
    gate_pool_mfma<<<cdiv(N, 64), TB, 0, stream>>>(bufB, wt_g1, g_b1, g_w2, g_b2,
                                                   batch, pg, gden, pooled, N);
    dec_prep<<<16, 64, 0, stream>>>(pooled, gden, W_d0, a_s_d0, a_d_d0, hd016, es16, ed16);

    // ---- decoder layer 0 (H=1, relu) + fused dec1 scores ----
    gat_gather_d08s<<<nodeWaveGrid, TB, 0, stream>>>(
        hd016, es16, ed16, off, esrc, batch, b_d0, ws_d1, wd_d1, bufA, es, ed, N);

    // ---- decoder layer 1 (H=1, C=128, no relu): z-path -> d_out ----
    gat_gather_z8<<<nodeWaveGrid, TB, 0, stream>>>(bufA, es, ed, off, esrc, h16 /*z*/, N);
    {
        dim3 grid(2, cdiv(N, 64));
        gemm_kt<64, float, false><<<grid, TB, 0, stream>>>(h16 /*z*/, wst_d1, b_d1, (float*)d_out, N, 128);
    }
}